// Round 1
// baseline (16289.163 us; speedup 1.0000x reference)
//
#include <hip/hip_runtime.h>
#include <math.h>

#define B_   1024
#define DIN  512
#define EMB  512
#define H_   1024
#define V_   4096
#define TSTEPS 32
#define LEN  33

#define BT 16    // batch rows per block
#define KC 128   // K chunk staged in LDS

// ---------------------------------------------------------------------------
// out[rb+r][col] = act( A1@W1 + A2@W2 + b1 + b2 ), N = 1024 cols, 1 col/thread
// ---------------------------------------------------------------------------
__global__ __launch_bounds__(256) void k_gemm(
    float* __restrict__ out,
    const float* __restrict__ A1, int K1, const float* __restrict__ W1,
    const float* __restrict__ A2, int K2, const float* __restrict__ W2,
    const float* __restrict__ b1, const float* __restrict__ b2,
    int do_tanh)
{
  const int N = H_;
  __shared__ float sA[BT][KC];
  const int tid = threadIdx.x;
  const int rb  = blockIdx.x * BT;
  const int col = blockIdx.y * 256 + tid;

  float acc[BT];
  float bias = b1[col] + (b2 ? b2[col] : 0.0f);
#pragma unroll
  for (int r = 0; r < BT; ++r) acc[r] = bias;

  const int nch = (K1 + K2) / KC;
  for (int c = 0; c < nch; ++c) {
    const int kb = c * KC;
    const float* A; const float* W; int k0, strideA;
    if (kb < K1) { A = A1; W = W1; k0 = kb;       strideA = K1; }
    else         { A = A2; W = W2; k0 = kb - K1;  strideA = K2; }
    __syncthreads();
    float4* s4 = (float4*)sA;
#pragma unroll
    for (int i = 0; i < (BT * KC / 4) / 256; ++i) {
      int idx = tid + i * 256;
      int r = idx >> 5, kk = (idx & 31) << 2;
      s4[idx] = *(const float4*)(A + (size_t)(rb + r) * strideA + k0 + kk);
    }
    __syncthreads();
    const float* Wp = W + (size_t)k0 * N + col;
#pragma unroll 2
    for (int k = 0; k < KC; k += 4) {
      float4 a[BT];
#pragma unroll
      for (int r = 0; r < BT; ++r) a[r] = *((const float4*)sA[r] + (k >> 2));
#pragma unroll
      for (int u = 0; u < 4; ++u) {
        float w = Wp[(size_t)(k + u) * N];
#pragma unroll
        for (int r = 0; r < BT; ++r)
          acc[r] = fmaf(((const float*)&a[r])[u], w, acc[r]);
      }
    }
  }
#pragma unroll
  for (int r = 0; r < BT; ++r) {
    float v = acc[r];
    if (do_tanh) v = tanhf(v);
    out[(size_t)(rb + r) * N + col] = v;
  }
}

// ---------------------------------------------------------------------------
// logits = h@W_out + b_out over a 1024-col vocab slice; fused streaming stats.
// 256 threads, 4 cols/thread (stride 256). Writes per-(row,slice) partials:
//   {m = slice max, s = sum e^{l-m}, t = sum (l-m)e^{l-m}, idx = argmax}
// ---------------------------------------------------------------------------
__global__ __launch_bounds__(256) void k_logits(
    const float* __restrict__ h, const float* __restrict__ Wout,
    const float* __restrict__ bout, float4* __restrict__ part)
{
  __shared__ float sA[BT][KC];
  __shared__ float redf[4][BT];
  __shared__ float redf2[4][BT];
  __shared__ int   redi[4][BT];
  __shared__ float bm[BT];
  __shared__ int   bix[BT];

  const int tid = threadIdx.x;
  const int rb  = blockIdx.x * BT;
  const int cb  = blockIdx.y * 1024;
  const int c0  = cb + tid;

  float acc[BT][4];
  float bj[4];
#pragma unroll
  for (int j = 0; j < 4; ++j) bj[j] = bout[c0 + j * 256];
#pragma unroll
  for (int r = 0; r < BT; ++r)
#pragma unroll
    for (int j = 0; j < 4; ++j) acc[r][j] = bj[j];

  for (int kb = 0; kb < H_; kb += KC) {
    __syncthreads();
    float4* s4 = (float4*)sA;
#pragma unroll
    for (int i = 0; i < (BT * KC / 4) / 256; ++i) {
      int idx = tid + i * 256;
      int r = idx >> 5, kk = (idx & 31) << 2;
      s4[idx] = *(const float4*)(h + (size_t)(rb + r) * H_ + kb + kk);
    }
    __syncthreads();
#pragma unroll 2
    for (int k = 0; k < KC; k += 4) {
      float4 a[BT];
#pragma unroll
      for (int r = 0; r < BT; ++r) a[r] = *((const float4*)sA[r] + (k >> 2));
#pragma unroll
      for (int u = 0; u < 4; ++u) {
        const float* wr = Wout + (size_t)(kb + k + u) * V_ + c0;
        float w0 = wr[0], w1 = wr[256], w2 = wr[512], w3 = wr[768];
#pragma unroll
        for (int r = 0; r < BT; ++r) {
          float av = ((const float*)&a[r])[u];
          acc[r][0] = fmaf(av, w0, acc[r][0]);
          acc[r][1] = fmaf(av, w1, acc[r][1]);
          acc[r][2] = fmaf(av, w2, acc[r][2]);
          acc[r][3] = fmaf(av, w3, acc[r][3]);
        }
      }
    }
  }

  const int wid = tid >> 6, lane = tid & 63;

  // pass A: per-row max + argmax (lowest index wins ties)
  float mx[BT]; int ix[BT];
#pragma unroll
  for (int r = 0; r < BT; ++r) {
    float m = acc[r][0]; int ii = c0;
#pragma unroll
    for (int j = 1; j < 4; ++j)
      if (acc[r][j] > m) { m = acc[r][j]; ii = c0 + j * 256; }
    mx[r] = m; ix[r] = ii;
  }
#pragma unroll
  for (int r = 0; r < BT; ++r) {
    for (int d = 32; d; d >>= 1) {
      float ov = __shfl_xor(mx[r], d);
      int   oi = __shfl_xor(ix[r], d);
      if (ov > mx[r] || (ov == mx[r] && oi < ix[r])) { mx[r] = ov; ix[r] = oi; }
    }
  }
  if (lane == 0) {
#pragma unroll
    for (int r = 0; r < BT; ++r) { redf[wid][r] = mx[r]; redi[wid][r] = ix[r]; }
  }
  __syncthreads();
  if (tid < BT) {
    float m = redf[0][tid]; int ii = redi[0][tid];
    for (int w = 1; w < 4; ++w) {
      float ov = redf[w][tid]; int oi = redi[w][tid];
      if (ov > m || (ov == m && oi < ii)) { m = ov; ii = oi; }
    }
    bm[tid] = m; bix[tid] = ii;
  }
  __syncthreads();

  // pass B: sums of e^{l-m} and (l-m)e^{l-m}
  float ss[BT], tt[BT];
#pragma unroll
  for (int r = 0; r < BT; ++r) {
    float m = bm[r];
    float s = 0.f, t = 0.f;
#pragma unroll
    for (int j = 0; j < 4; ++j) {
      float d = acc[r][j] - m;
      float e = expf(d);
      s += e; t += d * e;
    }
    ss[r] = s; tt[r] = t;
  }
#pragma unroll
  for (int r = 0; r < BT; ++r) {
    for (int d = 32; d; d >>= 1) {
      ss[r] += __shfl_xor(ss[r], d);
      tt[r] += __shfl_xor(tt[r], d);
    }
  }
  if (lane == 0) {
#pragma unroll
    for (int r = 0; r < BT; ++r) { redf[wid][r] = ss[r]; redf2[wid][r] = tt[r]; }
  }
  __syncthreads();
  if (tid < BT) {
    float s = 0.f, t = 0.f;
    for (int w = 0; w < 4; ++w) { s += redf[w][tid]; t += redf2[w][tid]; }
    part[(size_t)(rb + tid) * 4 + blockIdx.y] =
        make_float4(bm[tid], s, t, (float)bix[tid]);
  }
}

// ---------------------------------------------------------------------------
// Combine 4 vocab-slice partials per row; write seq/logp/entropy at column t;
// gather next input embedding.
// ---------------------------------------------------------------------------
__global__ __launch_bounds__(128) void k_finalize(
    const float4* __restrict__ part, const float* __restrict__ emb,
    float* __restrict__ out, float* __restrict__ inp, int t)
{
  const int row = blockIdx.x;
  __shared__ int s_tok;
  if (threadIdx.x == 0) {
    float4 p[4];
#pragma unroll
    for (int i = 0; i < 4; ++i) p[i] = part[(size_t)row * 4 + i];
    float m = p[0].x; int tok = (int)p[0].w;
#pragma unroll
    for (int i = 1; i < 4; ++i)
      if (p[i].x > m) { m = p[i].x; tok = (int)p[i].w; }
    float S = 0.f, T = 0.f;
#pragma unroll
    for (int i = 0; i < 4; ++i) {
      float w = expf(p[i].x - m);
      S += w * p[i].y;
      T += w * (p[i].z + (p[i].x - m) * p[i].y);
    }
    float lp  = -logf(S);
    float ent = logf(S) - T / S;
    out[(size_t)row * LEN + t]                 = (float)tok;
    out[(size_t)(B_ * LEN) + row * LEN + t]    = lp;
    out[(size_t)(2 * B_ * LEN) + row * LEN + t] = ent;
    s_tok = tok;
  }
  __syncthreads();
  const float4* src = (const float4*)(emb + (size_t)s_tok * EMB);
  float4* dst = (float4*)(inp + (size_t)row * EMB);
  for (int i = threadIdx.x; i < EMB / 4; i += blockDim.x) dst[i] = src[i];
}

// inp[b][:] = sos_embedding (float4 granularity)
__global__ void k_sos(const float* __restrict__ sos, float* __restrict__ inp) {
  int i = blockIdx.x * blockDim.x + threadIdx.x;   // float4 idx, B_*EMB/4 total
  ((float4*)inp)[i] = ((const float4*)sos)[i & (EMB / 4 - 1)];
}

// zero the force_eos column (LEN-1) of all three output sections
__global__ void k_zero(float* __restrict__ out) {
  int i = blockIdx.x * blockDim.x + threadIdx.x;
  if (i < 3 * B_) {
    int sec = i >> 10, row = i & (B_ - 1);
    out[(size_t)sec * (B_ * LEN) + (size_t)row * LEN + (LEN - 1)] = 0.f;
  }
}

extern "C" void kernel_launch(void* const* d_in, const int* in_sizes, int n_in,
                              void* d_out, int out_size, void* d_ws, size_t ws_size,
                              hipStream_t stream) {
  const float* x       = (const float*)d_in[0];
  const float* W_agent = (const float*)d_in[1];
  const float* b_agent = (const float*)d_in[2];
  const float* sos     = (const float*)d_in[3];
  const float* emb     = (const float*)d_in[4];
  const float* W_ih    = (const float*)d_in[5];
  const float* W_hh    = (const float*)d_in[6];
  const float* b_ih    = (const float*)d_in[7];
  const float* b_hh    = (const float*)d_in[8];
  const float* W_out   = (const float*)d_in[9];
  const float* b_out   = (const float*)d_in[10];
  float* out = (float*)d_out;

  float*  h0buf = (float*)d_ws;                       // [B][H]
  float*  h1buf = h0buf + (size_t)B_ * H_;            // [B][H]
  float*  inp   = h1buf + (size_t)B_ * H_;            // [B][EMB]
  float4* part  = (float4*)(inp + (size_t)B_ * EMB);  // [B][4]

  // inp0 = broadcast(sos); h0 = x @ W_agent + b_agent
  k_sos<<<dim3(B_ * EMB / 4 / 256), dim3(256), 0, stream>>>(sos, inp);
  k_gemm<<<dim3(B_ / BT, H_ / 256), dim3(256), 0, stream>>>(
      h0buf, x, DIN, W_agent, nullptr, 0, nullptr, b_agent, nullptr, 0);

  for (int t = 0; t < TSTEPS; ++t) {
    float* hr = (t & 1) ? h1buf : h0buf;
    float* hw = (t & 1) ? h0buf : h1buf;
    // h = tanh(inp@W_ih + h@W_hh + b_ih + b_hh)
    k_gemm<<<dim3(B_ / BT, H_ / 256), dim3(256), 0, stream>>>(
        hw, inp, EMB, W_ih, hr, H_, W_hh, b_ih, b_hh, 1);
    // logits + streaming softmax stats per vocab slice
    k_logits<<<dim3(B_ / BT, V_ / 1024), dim3(256), 0, stream>>>(
        hw, W_out, b_out, part);
    // combine slices, emit outputs, gather next embedding
    k_finalize<<<dim3(B_), dim3(128), 0, stream>>>(part, emb, out, inp, t);
  }
  k_zero<<<dim3(12), dim3(256), 0, stream>>>(out);
}

// Round 2
// 9970.225 us; speedup vs baseline: 1.6338x; 1.6338x over previous
//
#include <hip/hip_runtime.h>
#include <math.h>

#define B_   1024
#define DIN  512
#define EMB  512
#define H_   1024
#define V_   4096
#define TSTEPS 32
#define LEN  33

#define KC 128   // K chunk staged in LDS

// ---------------------------------------------------------------------------
// h-update GEMM: out[rb+r][col] = act(A1@W1 + A2@W2 + b1 + b2), N = 1024.
// BT=8 rows/block, 1 col/thread, grid (128, 4) = 512 blocks (2 per CU).
// ---------------------------------------------------------------------------
#define GBT 8
__global__ __launch_bounds__(256) void k_gemm(
    float* __restrict__ out,
    const float* __restrict__ A1, int K1, const float* __restrict__ W1,
    const float* __restrict__ A2, int K2, const float* __restrict__ W2,
    const float* __restrict__ b1, const float* __restrict__ b2,
    int do_tanh)
{
  const int N = H_;
  __shared__ float sA[GBT][KC];
  const int tid = threadIdx.x;
  const int rb  = blockIdx.x * GBT;
  const int col = blockIdx.y * 256 + tid;

  float acc[GBT];
  float bias = b1[col] + (b2 ? b2[col] : 0.0f);
#pragma unroll
  for (int r = 0; r < GBT; ++r) acc[r] = bias;

  const int nch = (K1 + K2) / KC;
  for (int c = 0; c < nch; ++c) {
    const int kb = c * KC;
    const float* A; const float* W; int k0, strideA;
    if (kb < K1) { A = A1; W = W1; k0 = kb;       strideA = K1; }
    else         { A = A2; W = W2; k0 = kb - K1;  strideA = K2; }
    __syncthreads();
    {  // 8 rows * 32 float4 = 256 float4 loads, one per thread
      float4* s4 = (float4*)sA;
      int r = tid >> 5, kk = (tid & 31) << 2;
      s4[tid] = *(const float4*)(A + (size_t)(rb + r) * strideA + k0 + kk);
    }
    __syncthreads();
    const float* Wp = W + (size_t)k0 * N + col;
#pragma unroll 4
    for (int k = 0; k < KC; k += 4) {
      float4 a[GBT];
#pragma unroll
      for (int r = 0; r < GBT; ++r) a[r] = *((const float4*)sA[r] + (k >> 2));
      float w[4];
#pragma unroll
      for (int u = 0; u < 4; ++u) w[u] = Wp[(size_t)(k + u) * N];
#pragma unroll
      for (int u = 0; u < 4; ++u)
#pragma unroll
        for (int r = 0; r < GBT; ++r)
          acc[r] = fmaf(((const float*)&a[r])[u], w[u], acc[r]);
    }
  }
#pragma unroll
  for (int r = 0; r < GBT; ++r) {
    float v = acc[r];
    if (do_tanh) v = tanhf(v);
    out[(size_t)(rb + r) * N + col] = v;
  }
}

// ---------------------------------------------------------------------------
// logits = h@W_out + b_out over a 512-col vocab slice; fused streaming stats.
// BT=16 rows/block, 2 ADJACENT cols/thread (float2 W loads), grid (64, 8).
// Writes per-(row,slice) partials {m, sum e^{l-m}, sum (l-m)e^{l-m}, argmax}.
// ---------------------------------------------------------------------------
#define BT 16
__global__ __launch_bounds__(256) void k_logits(
    const float* __restrict__ h, const float* __restrict__ Wout,
    const float* __restrict__ bout, float4* __restrict__ part)
{
  __shared__ float sA[BT][KC];
  __shared__ float redf[4][BT];
  __shared__ float redf2[4][BT];
  __shared__ int   redi[4][BT];
  __shared__ float bm[BT];
  __shared__ int   bix[BT];

  const int tid = threadIdx.x;
  const int rb  = blockIdx.x * BT;
  const int c0  = blockIdx.y * 512 + tid * 2;

  float acc[BT][2];
  float2 bj = *(const float2*)(bout + c0);
#pragma unroll
  for (int r = 0; r < BT; ++r) { acc[r][0] = bj.x; acc[r][1] = bj.y; }

  for (int kb = 0; kb < H_; kb += KC) {
    __syncthreads();
    {  // 16 rows * 32 float4 = 512 float4 loads
      float4* s4 = (float4*)sA;
#pragma unroll
      for (int i = 0; i < 2; ++i) {
        int idx = tid + i * 256;
        int r = idx >> 5, kk = (idx & 31) << 2;
        s4[idx] = *(const float4*)(h + (size_t)(rb + r) * H_ + kb + kk);
      }
    }
    __syncthreads();
    const float* Wp = Wout + (size_t)kb * V_ + c0;
#pragma unroll 2
    for (int k = 0; k < KC; k += 4) {
      float4 a[BT];
#pragma unroll
      for (int r = 0; r < BT; ++r) a[r] = *((const float4*)sA[r] + (k >> 2));
      float2 w[4];
#pragma unroll
      for (int u = 0; u < 4; ++u)
        w[u] = *(const float2*)(Wp + (size_t)(k + u) * V_);
#pragma unroll
      for (int u = 0; u < 4; ++u)
#pragma unroll
        for (int r = 0; r < BT; ++r) {
          float av = ((const float*)&a[r])[u];
          acc[r][0] = fmaf(av, w[u].x, acc[r][0]);
          acc[r][1] = fmaf(av, w[u].y, acc[r][1]);
        }
    }
  }

  const int wid = tid >> 6, lane = tid & 63;

  // pass A: per-row max + argmax (lowest index wins ties)
  float mx[BT]; int ix[BT];
#pragma unroll
  for (int r = 0; r < BT; ++r) {
    float m = acc[r][0]; int ii = c0;
    if (acc[r][1] > m) { m = acc[r][1]; ii = c0 + 1; }
    mx[r] = m; ix[r] = ii;
  }
#pragma unroll
  for (int r = 0; r < BT; ++r) {
    for (int d = 32; d; d >>= 1) {
      float ov = __shfl_xor(mx[r], d);
      int   oi = __shfl_xor(ix[r], d);
      if (ov > mx[r] || (ov == mx[r] && oi < ix[r])) { mx[r] = ov; ix[r] = oi; }
    }
  }
  if (lane == 0) {
#pragma unroll
    for (int r = 0; r < BT; ++r) { redf[wid][r] = mx[r]; redi[wid][r] = ix[r]; }
  }
  __syncthreads();
  if (tid < BT) {
    float m = redf[0][tid]; int ii = redi[0][tid];
    for (int w = 1; w < 4; ++w) {
      float ov = redf[w][tid]; int oi = redi[w][tid];
      if (ov > m || (ov == m && oi < ii)) { m = ov; ii = oi; }
    }
    bm[tid] = m; bix[tid] = ii;
  }
  __syncthreads();

  // pass B: sums of e^{l-m} and (l-m)e^{l-m}
  float ss[BT], tt[BT];
#pragma unroll
  for (int r = 0; r < BT; ++r) {
    float m = bm[r];
    float s = 0.f, t = 0.f;
#pragma unroll
    for (int j = 0; j < 2; ++j) {
      float d = acc[r][j] - m;
      float e = expf(d);
      s += e; t += d * e;
    }
    ss[r] = s; tt[r] = t;
  }
#pragma unroll
  for (int r = 0; r < BT; ++r) {
    for (int d = 32; d; d >>= 1) {
      ss[r] += __shfl_xor(ss[r], d);
      tt[r] += __shfl_xor(tt[r], d);
    }
  }
  if (lane == 0) {
#pragma unroll
    for (int r = 0; r < BT; ++r) { redf[wid][r] = ss[r]; redf2[wid][r] = tt[r]; }
  }
  __syncthreads();
  if (tid < BT) {
    float s = 0.f, t = 0.f;
    for (int w = 0; w < 4; ++w) { s += redf[w][tid]; t += redf2[w][tid]; }
    part[(size_t)(rb + tid) * 8 + blockIdx.y] =
        make_float4(bm[tid], s, t, (float)bix[tid]);
  }
}

// ---------------------------------------------------------------------------
// Combine 8 vocab-slice partials per row; write seq/logp/entropy at column t;
// gather next input embedding.
// ---------------------------------------------------------------------------
__global__ __launch_bounds__(128) void k_finalize(
    const float4* __restrict__ part, const float* __restrict__ emb,
    float* __restrict__ out, float* __restrict__ inp, int t)
{
  const int row = blockIdx.x;
  __shared__ int s_tok;
  if (threadIdx.x == 0) {
    float4 p[8];
#pragma unroll
    for (int i = 0; i < 8; ++i) p[i] = part[(size_t)row * 8 + i];
    float m = p[0].x; int tok = (int)p[0].w;
#pragma unroll
    for (int i = 1; i < 8; ++i)
      if (p[i].x > m) { m = p[i].x; tok = (int)p[i].w; }
    float S = 0.f, T = 0.f;
#pragma unroll
    for (int i = 0; i < 8; ++i) {
      float w = expf(p[i].x - m);
      S += w * p[i].y;
      T += w * (p[i].z + (p[i].x - m) * p[i].y);
    }
    float lp  = -logf(S);
    float ent = logf(S) - T / S;
    out[(size_t)row * LEN + t]                  = (float)tok;
    out[(size_t)(B_ * LEN) + row * LEN + t]     = lp;
    out[(size_t)(2 * B_ * LEN) + row * LEN + t] = ent;
    s_tok = tok;
  }
  __syncthreads();
  const float4* src = (const float4*)(emb + (size_t)s_tok * EMB);
  float4* dst = (float4*)(inp + (size_t)row * EMB);
  for (int i = threadIdx.x; i < EMB / 4; i += blockDim.x) dst[i] = src[i];
}

// inp[b][:] = sos_embedding (float4 granularity)
__global__ void k_sos(const float* __restrict__ sos, float* __restrict__ inp) {
  int i = blockIdx.x * blockDim.x + threadIdx.x;   // float4 idx, B_*EMB/4 total
  ((float4*)inp)[i] = ((const float4*)sos)[i & (EMB / 4 - 1)];
}

// zero the force_eos column (LEN-1) of all three output sections
__global__ void k_zero(float* __restrict__ out) {
  int i = blockIdx.x * blockDim.x + threadIdx.x;
  if (i < 3 * B_) {
    int sec = i >> 10, row = i & (B_ - 1);
    out[(size_t)sec * (B_ * LEN) + (size_t)row * LEN + (LEN - 1)] = 0.f;
  }
}

extern "C" void kernel_launch(void* const* d_in, const int* in_sizes, int n_in,
                              void* d_out, int out_size, void* d_ws, size_t ws_size,
                              hipStream_t stream) {
  const float* x       = (const float*)d_in[0];
  const float* W_agent = (const float*)d_in[1];
  const float* b_agent = (const float*)d_in[2];
  const float* sos     = (const float*)d_in[3];
  const float* emb     = (const float*)d_in[4];
  const float* W_ih    = (const float*)d_in[5];
  const float* W_hh    = (const float*)d_in[6];
  const float* b_ih    = (const float*)d_in[7];
  const float* b_hh    = (const float*)d_in[8];
  const float* W_out   = (const float*)d_in[9];
  const float* b_out   = (const float*)d_in[10];
  float* out = (float*)d_out;

  float*  h0buf = (float*)d_ws;                       // [B][H]
  float*  h1buf = h0buf + (size_t)B_ * H_;            // [B][H]
  float*  inp   = h1buf + (size_t)B_ * H_;            // [B][EMB]
  float4* part  = (float4*)(inp + (size_t)B_ * EMB);  // [B][8]

  // inp0 = broadcast(sos); h0 = x @ W_agent + b_agent
  k_sos<<<dim3(B_ * EMB / 4 / 256), dim3(256), 0, stream>>>(sos, inp);
  k_gemm<<<dim3(B_ / GBT, H_ / 256), dim3(256), 0, stream>>>(
      h0buf, x, DIN, W_agent, nullptr, 0, nullptr, b_agent, nullptr, 0);

  for (int t = 0; t < TSTEPS; ++t) {
    float* hr = (t & 1) ? h1buf : h0buf;
    float* hw = (t & 1) ? h0buf : h1buf;
    // h = tanh(inp@W_ih + h@W_hh + b_ih + b_hh)
    k_gemm<<<dim3(B_ / GBT, H_ / 256), dim3(256), 0, stream>>>(
        hw, inp, EMB, W_ih, hr, H_, W_hh, b_ih, b_hh, 1);
    // logits + streaming softmax stats per 512-col vocab slice
    k_logits<<<dim3(B_ / BT, V_ / 512), dim3(256), 0, stream>>>(
        hw, W_out, b_out, part);
    // combine slices, emit outputs, gather next embedding
    k_finalize<<<dim3(B_), dim3(128), 0, stream>>>(part, emb, out, inp, t);
  }
  k_zero<<<dim3(12), dim3(256), 0, stream>>>(out);
}

// Round 3
// 5253.089 us; speedup vs baseline: 3.1009x; 1.8980x over previous
//
#include <hip/hip_runtime.h>
#include <math.h>

#define B_   1024
#define DIN  512
#define EMB  512
#define H_   1024
#define V_   4096
#define TSTEPS 32
#define LEN  33

typedef __attribute__((ext_vector_type(8))) short short8_t;
typedef __attribute__((ext_vector_type(4))) float f32x4;

__device__ inline unsigned short bf16_rne(float f) {
  unsigned u = __builtin_bit_cast(unsigned, f);
  u += 0x7FFFu + ((u >> 16) & 1u);
  return (unsigned short)(u >> 16);
}
__device__ inline float bf16_to_f(unsigned short h) {
  unsigned u = ((unsigned)h) << 16;
  return __builtin_bit_cast(float, u);
}

// ===========================================================================
// h-update GEMM (fp32, bit-stable h chain): out = act(A1@W1 + A2@W2 + b1+b2)
// BT=4 rows/block, 1 col/thread, 1024 blocks (XCD-swizzled) = 4 blk/CU.
// ===========================================================================
#define GBT 4
#define GKC 256
__global__ __launch_bounds__(256) void k_gemm(
    float* __restrict__ out,
    const float* __restrict__ A1, int K1, const float* __restrict__ W1,
    const float* __restrict__ A2, int K2, const float* __restrict__ W2,
    const float* __restrict__ b1, const float* __restrict__ b2,
    int do_tanh)
{
  const int N = H_;
  __shared__ float sA[GBT][GKC];
  const int tid = threadIdx.x;
  const int bid = blockIdx.x;
  const int colb = (bid & 7) >> 1;                 // 0..3 : XCD pairs share a col-slice
  const int rowb = ((bid >> 3) << 1) | (bid & 1);  // 0..255
  const int rb  = rowb * GBT;
  const int col = colb * 256 + tid;

  float acc[GBT];
  float bias = b1[col] + (b2 ? b2[col] : 0.0f);
#pragma unroll
  for (int r = 0; r < GBT; ++r) acc[r] = bias;

  const int nch = (K1 + K2) / GKC;
  for (int c = 0; c < nch; ++c) {
    const int kb = c * GKC;
    const float* A; const float* W; int k0, strideA;
    if (kb < K1) { A = A1; W = W1; k0 = kb;      strideA = K1; }
    else         { A = A2; W = W2; k0 = kb - K1; strideA = K2; }
    __syncthreads();
    {
      int r = tid >> 6, kk = (tid & 63) << 2;
      *(float4*)&sA[r][kk] = *(const float4*)(A + (size_t)(rb + r) * strideA + k0 + kk);
    }
    __syncthreads();
    const float* Wp = W + (size_t)k0 * N + col;
#pragma unroll 4
    for (int k = 0; k < GKC; k += 4) {
      float4 a0 = *(const float4*)&sA[0][k];
      float4 a1 = *(const float4*)&sA[1][k];
      float4 a2 = *(const float4*)&sA[2][k];
      float4 a3 = *(const float4*)&sA[3][k];
      float w0 = Wp[(size_t)k * N];
      float w1 = Wp[(size_t)(k + 1) * N];
      float w2 = Wp[(size_t)(k + 2) * N];
      float w3 = Wp[(size_t)(k + 3) * N];
      acc[0] = fmaf(a0.x, w0, acc[0]); acc[1] = fmaf(a1.x, w0, acc[1]);
      acc[2] = fmaf(a2.x, w0, acc[2]); acc[3] = fmaf(a3.x, w0, acc[3]);
      acc[0] = fmaf(a0.y, w1, acc[0]); acc[1] = fmaf(a1.y, w1, acc[1]);
      acc[2] = fmaf(a2.y, w1, acc[2]); acc[3] = fmaf(a3.y, w1, acc[3]);
      acc[0] = fmaf(a0.z, w2, acc[0]); acc[1] = fmaf(a1.z, w2, acc[1]);
      acc[2] = fmaf(a2.z, w2, acc[2]); acc[3] = fmaf(a3.z, w2, acc[3]);
      acc[0] = fmaf(a0.w, w3, acc[0]); acc[1] = fmaf(a1.w, w3, acc[1]);
      acc[2] = fmaf(a2.w, w3, acc[2]); acc[3] = fmaf(a3.w, w3, acc[3]);
    }
  }
#pragma unroll
  for (int r = 0; r < GBT; ++r) {
    float v = acc[r];
    if (do_tanh) v = tanhf(v);
    out[(size_t)(rb + r) * N + col] = v;
  }
}

// ===========================================================================
// One-time pre-pack of W_out into bf16 hi/lo planes, MFMA B-fragment order:
// Bp[p][ks][ntg][lane] (short8) = W[ks*32+(lane>>4)*8+j][ntg*16+(lane&15)]
// ===========================================================================
__global__ __launch_bounds__(256) void k_prepack(
    const float* __restrict__ W, unsigned short* __restrict__ Bp)
{
  int t = blockIdx.x * 256 + threadIdx.x;   // 524288 threads
  int lane = t & 63;
  int ntg  = (t >> 6) & 255;
  int ks   = t >> 14;                        // 0..31
  int col  = ntg * 16 + (lane & 15);
  int krow = ks * 32 + ((lane >> 4) << 3);
  short8_t hv, lv;
#pragma unroll
  for (int j = 0; j < 8; ++j) {
    float w = W[(size_t)(krow + j) * V_ + col];
    unsigned short h = bf16_rne(w);
    hv[j] = (short)h;
    lv[j] = (short)bf16_rne(w - bf16_to_f(h));
  }
  size_t base = ((size_t)ks * 256 + ntg) * 64 + lane;  // short8 units
  short8_t* o = (short8_t*)Bp;
  o[base]          = hv;
  o[base + 524288] = lv;   // lo plane (32*256*64 short8 per plane)
}

// ===========================================================================
// logits via split-bf16 MFMA (3 mfma_f32_16x16x32_bf16 per fragment pair).
// Block: 256 thr = 4 waves (2x2), tile M=32 x N=128. Grid 1024, XCD-swizzled.
// Epilogue: per-row top-2 (val+idx) + exp-sum partials per 128-col block.
// ===========================================================================
#define LKC 256
__global__ __launch_bounds__(256) void k_logits_mfma(
    const float* __restrict__ h, const unsigned short* __restrict__ Bp,
    const float* __restrict__ bout, float4* __restrict__ partA,
    float4* __restrict__ partB)
{
  __shared__ unsigned short sAh[32 * LKC];   // hi plane, XOR-swizzled, 16KB
  __shared__ unsigned short sAl[32 * LKC];   // lo plane, 16KB
  __shared__ float sred[2][2][16][8];        // [wm][wn][row16][{m1,i1,m2,i2,s,t,..}]
  __shared__ float sbmax[32];

  const int bid  = blockIdx.x;
  const int colb = (bid & 7) * 4 + ((bid >> 3) & 3);  // 0..31, XCD-local slices
  const int rowb = bid >> 5;                           // 0..31
  const int tid  = threadIdx.x;
  const int lane = tid & 63;
  const int wid  = tid >> 6;
  const int wm = wid >> 1, wn = wid & 1;
  const int l15 = lane & 15, lg = lane >> 4;

  const int colbase = colb * 128 + wn * 64;
  f32x4 acc[4];
#pragma unroll
  for (int nt = 0; nt < 4; ++nt) {
    float b = bout[colbase + nt * 16 + l15];
    acc[nt] = (f32x4){b, b, b, b};
  }

  const int arow = wm * 16 + l15;
  for (int kc = 0; kc < 4; ++kc) {
    const int k0 = kc * LKC;
    __syncthreads();
    {  // stage A chunk: thread t -> row r=t>>3, 32 k's at (t&7)*32
      int r = tid >> 3, kk = (tid & 7) * 32;
      const float* src = h + (size_t)(rowb * 32 + r) * H_ + k0 + kk;
#pragma unroll
      for (int i = 0; i < 4; ++i) {
        float4 f0 = *(const float4*)(src + i * 8);
        float4 f1 = *(const float4*)(src + i * 8 + 4);
        float ff[8] = {f0.x, f0.y, f0.z, f0.w, f1.x, f1.y, f1.z, f1.w};
        short8_t hv, lv;
#pragma unroll
        for (int j = 0; j < 8; ++j) {
          unsigned short hh = bf16_rne(ff[j]);
          hv[j] = (short)hh;
          lv[j] = (short)bf16_rne(ff[j] - bf16_to_f(hh));
        }
        unsigned off = ((unsigned)(r * 512 + (kk + i * 8) * 2)) ^ ((unsigned)((r & 7) << 4));
        *(short8_t*)((char*)sAh + off) = hv;
        *(short8_t*)((char*)sAl + off) = lv;
      }
    }
    __syncthreads();
#pragma unroll
    for (int kk = 0; kk < 8; ++kk) {
      unsigned off = ((unsigned)(arow * 512 + kk * 64 + lg * 16)) ^ ((unsigned)((arow & 7) << 4));
      short8_t ahi = *(const short8_t*)((const char*)sAh + off);
      short8_t alo = *(const short8_t*)((const char*)sAl + off);
      const int ks = kc * 8 + kk;
      const short8_t* bp = (const short8_t*)Bp;
      size_t bb = ((size_t)ks * 256 + (size_t)(colb * 8 + wn * 4)) * 64 + lane;
#pragma unroll
      for (int nt = 0; nt < 4; ++nt) {
        short8_t bhi = bp[bb + nt * 64];
        short8_t blo = bp[bb + nt * 64 + 524288];
        acc[nt] = __builtin_amdgcn_mfma_f32_16x16x32_bf16(ahi, bhi, acc[nt], 0, 0, 0);
        acc[nt] = __builtin_amdgcn_mfma_f32_16x16x32_bf16(ahi, blo, acc[nt], 0, 0, 0);
        acc[nt] = __builtin_amdgcn_mfma_f32_16x16x32_bf16(alo, bhi, acc[nt], 0, 0, 0);
      }
    }
  }

  // ---- epilogue. C layout: col = l15, row = lg*4 + r (m89-verified) ----
  // phase 1: per-row top2 over this wave's 64 cols
  float m1[4], m2[4]; int i1[4], i2[4];
#pragma unroll
  for (int r = 0; r < 4; ++r) {
    m1[r] = -1e30f; m2[r] = -1e30f; i1[r] = 0; i2[r] = 0;
#pragma unroll
    for (int nt = 0; nt < 4; ++nt) {
      float v = acc[nt][r]; int c = colbase + nt * 16 + l15;
      if (v > m1[r]) { m2[r] = m1[r]; i2[r] = i1[r]; m1[r] = v; i1[r] = c; }
      else if (v > m2[r]) { m2[r] = v; i2[r] = c; }
    }
#pragma unroll
    for (int d = 1; d < 16; d <<= 1) {
      float om1 = __shfl_xor(m1[r], d); int oi1 = __shfl_xor(i1[r], d);
      float om2 = __shfl_xor(m2[r], d); int oi2 = __shfl_xor(i2[r], d);
      if (om1 > m1[r] || (om1 == m1[r] && oi1 < i1[r])) {
        float nm2; int ni2;
        if (m1[r] > om2 || (m1[r] == om2 && i1[r] < oi2)) { nm2 = m1[r]; ni2 = i1[r]; }
        else { nm2 = om2; ni2 = oi2; }
        m1[r] = om1; i1[r] = oi1; m2[r] = nm2; i2[r] = ni2;
      } else if (om1 > m2[r] || (om1 == m2[r] && oi1 < i2[r])) {
        m2[r] = om1; i2[r] = oi1;
      }
    }
  }
  if (l15 == 0) {
#pragma unroll
    for (int r = 0; r < 4; ++r) {
      int rl = lg * 4 + r;
      sred[wm][wn][rl][0] = m1[r];
      sred[wm][wn][rl][1] = (float)i1[r];
      sred[wm][wn][rl][2] = m2[r];
      sred[wm][wn][rl][3] = (float)i2[r];
    }
  }
  __syncthreads();
  if (tid < 32) {
    int wmm = tid >> 4, rl = tid & 15;
    float a1 = sred[wmm][0][rl][0]; int a1i = (int)sred[wmm][0][rl][1];
    float a2 = sred[wmm][0][rl][2]; int a2i = (int)sred[wmm][0][rl][3];
    float c1 = sred[wmm][1][rl][0]; int c1i = (int)sred[wmm][1][rl][1];
    float c2 = sred[wmm][1][rl][2]; int c2i = (int)sred[wmm][1][rl][3];
    float M1, M2; int I1, I2;
    if (a1 > c1 || (a1 == c1 && a1i < c1i)) {
      M1 = a1; I1 = a1i;
      if (c1 > a2 || (c1 == a2 && c1i < a2i)) { M2 = c1; I2 = c1i; }
      else { M2 = a2; I2 = a2i; }
    } else {
      M1 = c1; I1 = c1i;
      if (a1 > c2 || (a1 == c2 && a1i < c2i)) { M2 = a1; I2 = a1i; }
      else { M2 = c2; I2 = c2i; }
    }
    int row = rowb * 32 + wmm * 16 + rl;
    partA[(size_t)row * 32 + colb] = make_float4(M1, (float)I1, M2, (float)I2);
    sbmax[wmm * 16 + rl] = M1;
  }
  __syncthreads();
  // phase 2: exp sums relative to block max
#pragma unroll
  for (int r = 0; r < 4; ++r) {
    float m = sbmax[wm * 16 + lg * 4 + r];
    float s = 0.f, tsum = 0.f;
#pragma unroll
    for (int nt = 0; nt < 4; ++nt) {
      float d = acc[nt][r] - m;
      float e = expf(d);
      s += e; tsum += d * e;
    }
#pragma unroll
    for (int d = 1; d < 16; d <<= 1) { s += __shfl_xor(s, d); tsum += __shfl_xor(tsum, d); }
    if (l15 == 0) { sred[wm][wn][lg * 4 + r][4] = s; sred[wm][wn][lg * 4 + r][5] = tsum; }
  }
  __syncthreads();
  if (tid < 32) {
    int wmm = tid >> 4, rl = tid & 15;
    float s = sred[wmm][0][rl][4] + sred[wmm][1][rl][4];
    float tsum = sred[wmm][0][rl][5] + sred[wmm][1][rl][5];
    int row = rowb * 32 + wmm * 16 + rl;
    partB[(size_t)row * 32 + colb] = make_float4(s, tsum, 0.f, 0.f);
  }
}

// ===========================================================================
// Finalize: merge 32 col-block partials/row, fp32-recompute top-2 candidate
// logits (exact argmax), emit seq/logp/entropy, gather next embedding.
// One wave per row; grid 256 x 256 threads.
// ===========================================================================
__global__ __launch_bounds__(256) void k_finalize2(
    const float4* __restrict__ partA, const float4* __restrict__ partB,
    const float* __restrict__ h, const float* __restrict__ Wout,
    const float* __restrict__ bout, const float* __restrict__ emb,
    float* __restrict__ out, float* __restrict__ inp, int tstep)
{
  const int lane = threadIdx.x & 63;
  const int wid  = threadIdx.x >> 6;
  const int row  = blockIdx.x * 4 + wid;

  float M1 = -1e30f, M2 = -1e30f; int I1 = 0, I2 = 0;
  float bm = -1e30f, s_l = 0.f, t_l = 0.f;
  if (lane < 32) {
    float4 pa = partA[(size_t)row * 32 + lane];
    float4 pb = partB[(size_t)row * 32 + lane];
    M1 = pa.x; I1 = (int)pa.y; M2 = pa.z; I2 = (int)pa.w;
    bm = pa.x; s_l = pb.x; t_l = pb.y;
  }
  for (int d = 1; d < 32; d <<= 1) {
    float om1 = __shfl_xor(M1, d); int oi1 = __shfl_xor(I1, d);
    float om2 = __shfl_xor(M2, d); int oi2 = __shfl_xor(I2, d);
    if (om1 > M1 || (om1 == M1 && oi1 < I1)) {
      float nm2; int ni2;
      if (M1 > om2 || (M1 == om2 && I1 < oi2)) { nm2 = M1; ni2 = I1; }
      else { nm2 = om2; ni2 = oi2; }
      M1 = om1; I1 = oi1; M2 = nm2; I2 = ni2;
    } else if (om1 > M2 || (om1 == M2 && oi1 < I2)) {
      M2 = om1; I2 = oi1;
    }
  }
  M1 = __shfl(M1, 0); I1 = __shfl(I1, 0);
  M2 = __shfl(M2, 0); I2 = __shfl(I2, 0);

  float e = (lane < 32) ? expf(bm - M1) : 0.f;
  float s = e * s_l;
  float tsum = e * (t_l + (bm - M1) * s_l);
  for (int d = 1; d < 64; d <<= 1) { s += __shfl_xor(s, d); tsum += __shfl_xor(tsum, d); }

  // exact fp32 dots for the two candidates
  const float* hrow = h + (size_t)row * H_;
  float d1 = 0.f, d2 = 0.f;
  for (int k = lane; k < H_; k += 64) {
    float hv = hrow[k];
    d1 = fmaf(hv, Wout[(size_t)k * V_ + I1], d1);
    d2 = fmaf(hv, Wout[(size_t)k * V_ + I2], d2);
  }
  for (int d = 1; d < 64; d <<= 1) { d1 += __shfl_xor(d1, d); d2 += __shfl_xor(d2, d); }
  d1 += bout[I1]; d2 += bout[I2];

  int tok; float ltok;
  if (d2 > d1 || (d2 == d1 && I2 < I1)) { tok = I2; ltok = d2; }
  else                                  { tok = I1; ltok = d1; }
  float lg_s = logf(s);
  if (lane == 0) {
    out[(size_t)row * LEN + tstep]                  = (float)tok;
    out[(size_t)(B_ * LEN) + row * LEN + tstep]     = ltok - M1 - lg_s;
    out[(size_t)(2 * B_ * LEN) + row * LEN + tstep] = lg_s - tsum / s;
  }
  const float4* src = (const float4*)(emb + (size_t)tok * EMB);
  float4* dst = (float4*)(inp + (size_t)row * EMB);
#pragma unroll
  for (int i = 0; i < 2; ++i) dst[lane + 64 * i] = src[lane + 64 * i];
}

// ============================ fp32 fallback path ===========================
#define BT 16
#define KC 128
__global__ __launch_bounds__(256) void k_logits_f32(
    const float* __restrict__ h, const float* __restrict__ Wout,
    const float* __restrict__ bout, float4* __restrict__ part)
{
  __shared__ float sA[BT][KC];
  __shared__ float redf[4][BT];
  __shared__ float redf2[4][BT];
  __shared__ int   redi[4][BT];
  __shared__ float bm[BT];

  const int tid = threadIdx.x;
  const int rb  = blockIdx.x * BT;
  const int c0  = blockIdx.y * 512 + tid * 2;

  float acc[BT][2];
  float2 bj = *(const float2*)(bout + c0);
#pragma unroll
  for (int r = 0; r < BT; ++r) { acc[r][0] = bj.x; acc[r][1] = bj.y; }

  for (int kb = 0; kb < H_; kb += KC) {
    __syncthreads();
    {
      float4* s4 = (float4*)sA;
#pragma unroll
      for (int i = 0; i < 2; ++i) {
        int idx = tid + i * 256;
        int r = idx >> 5, kk = (idx & 31) << 2;
        s4[idx] = *(const float4*)(h + (size_t)(rb + r) * H_ + kb + kk);
      }
    }
    __syncthreads();
    const float* Wp = Wout + (size_t)kb * V_ + c0;
#pragma unroll 2
    for (int k = 0; k < KC; k += 4) {
      float4 a[BT];
#pragma unroll
      for (int r = 0; r < BT; ++r) a[r] = *((const float4*)sA[r] + (k >> 2));
      float2 w[4];
#pragma unroll
      for (int u = 0; u < 4; ++u) w[u] = *(const float2*)(Wp + (size_t)(k + u) * V_);
#pragma unroll
      for (int u = 0; u < 4; ++u)
#pragma unroll
        for (int r = 0; r < BT; ++r) {
          float av = ((const float*)&a[r])[u];
          acc[r][0] = fmaf(av, w[u].x, acc[r][0]);
          acc[r][1] = fmaf(av, w[u].y, acc[r][1]);
        }
    }
  }

  const int wid = tid >> 6, lane = tid & 63;
  float mx[BT]; int ix[BT];
#pragma unroll
  for (int r = 0; r < BT; ++r) {
    float m = acc[r][0]; int ii = c0;
    if (acc[r][1] > m) { m = acc[r][1]; ii = c0 + 1; }
    mx[r] = m; ix[r] = ii;
  }
#pragma unroll
  for (int r = 0; r < BT; ++r) {
    for (int d = 32; d; d >>= 1) {
      float ov = __shfl_xor(mx[r], d);
      int   oi = __shfl_xor(ix[r], d);
      if (ov > mx[r] || (ov == mx[r] && oi < ix[r])) { mx[r] = ov; ix[r] = oi; }
    }
  }
  if (lane == 0) {
#pragma unroll
    for (int r = 0; r < BT; ++r) { redf[wid][r] = mx[r]; redi[wid][r] = ix[r]; }
  }
  __syncthreads();
  if (tid < BT) {
    float m = redf[0][tid]; int ii = redi[0][tid];
    for (int w = 1; w < 4; ++w) {
      float ov = redf[w][tid]; int oi = redi[w][tid];
      if (ov > m || (ov == m && oi < ii)) { m = ov; ii = oi; }
    }
    bm[tid] = m; redi[0][tid] = ii;
  }
  __syncthreads();
  float ss[BT], tt[BT];
#pragma unroll
  for (int r = 0; r < BT; ++r) {
    float m = bm[r];
    float s = 0.f, t = 0.f;
#pragma unroll
    for (int j = 0; j < 2; ++j) {
      float d = acc[r][j] - m;
      float e2 = expf(d);
      s += e2; t += d * e2;
    }
    ss[r] = s; tt[r] = t;
  }
#pragma unroll
  for (int r = 0; r < BT; ++r) {
    for (int d = 32; d; d >>= 1) {
      ss[r] += __shfl_xor(ss[r], d);
      tt[r] += __shfl_xor(tt[r], d);
    }
  }
  if (lane == 0) {
#pragma unroll
    for (int r = 0; r < BT; ++r) { redf[wid][r] = ss[r]; redf2[wid][r] = tt[r]; }
  }
  __syncthreads();
  if (tid < BT) {
    float s = 0.f, t = 0.f;
    for (int w = 0; w < 4; ++w) { s += redf[w][tid]; t += redf2[w][tid]; }
    part[(size_t)(rb + tid) * 8 + blockIdx.y] =
        make_float4(bm[tid], s, t, (float)redi[0][tid]);
  }
}

__global__ __launch_bounds__(128) void k_finalize_f32(
    const float4* __restrict__ part, const float* __restrict__ emb,
    float* __restrict__ out, float* __restrict__ inp, int t)
{
  const int row = blockIdx.x;
  __shared__ int s_tok;
  if (threadIdx.x == 0) {
    float4 p[8];
#pragma unroll
    for (int i = 0; i < 8; ++i) p[i] = part[(size_t)row * 8 + i];
    float m = p[0].x; int tok = (int)p[0].w;
#pragma unroll
    for (int i = 1; i < 8; ++i)
      if (p[i].x > m) { m = p[i].x; tok = (int)p[i].w; }
    float S = 0.f, T = 0.f;
#pragma unroll
    for (int i = 0; i < 8; ++i) {
      float w = expf(p[i].x - m);
      S += w * p[i].y;
      T += w * (p[i].z + (p[i].x - m) * p[i].y);
    }
    float lp  = -logf(S);
    float ent = logf(S) - T / S;
    out[(size_t)row * LEN + t]                  = (float)tok;
    out[(size_t)(B_ * LEN) + row * LEN + t]     = lp;
    out[(size_t)(2 * B_ * LEN) + row * LEN + t] = ent;
    s_tok = tok;
  }
  __syncthreads();
  const float4* src = (const float4*)(emb + (size_t)s_tok * EMB);
  float4* dst = (float4*)(inp + (size_t)row * EMB);
  for (int i = threadIdx.x; i < EMB / 4; i += blockDim.x) dst[i] = src[i];
}

// ============================ small utilities ==============================
__global__ void k_sos(const float* __restrict__ sos, float* __restrict__ inp) {
  int i = blockIdx.x * blockDim.x + threadIdx.x;
  ((float4*)inp)[i] = ((const float4*)sos)[i & (EMB / 4 - 1)];
}
__global__ void k_zero(float* __restrict__ out) {
  int i = blockIdx.x * blockDim.x + threadIdx.x;
  if (i < 3 * B_) {
    int sec = i >> 10, row = i & (B_ - 1);
    out[(size_t)sec * (B_ * LEN) + (size_t)row * LEN + (LEN - 1)] = 0.f;
  }
}

extern "C" void kernel_launch(void* const* d_in, const int* in_sizes, int n_in,
                              void* d_out, int out_size, void* d_ws, size_t ws_size,
                              hipStream_t stream) {
  const float* x       = (const float*)d_in[0];
  const float* W_agent = (const float*)d_in[1];
  const float* b_agent = (const float*)d_in[2];
  const float* sos     = (const float*)d_in[3];
  const float* emb     = (const float*)d_in[4];
  const float* W_ih    = (const float*)d_in[5];
  const float* W_hh    = (const float*)d_in[6];
  const float* b_ih    = (const float*)d_in[7];
  const float* b_hh    = (const float*)d_in[8];
  const float* W_out   = (const float*)d_in[9];
  const float* b_out   = (const float*)d_in[10];
  float* out = (float*)d_out;

  const size_t BP_BYTES = 2ull * 32 * 256 * 64 * 16;  // 16,777,216
  const size_t NEED = BP_BYTES + 2ull * B_ * H_ * 4 + (size_t)B_ * EMB * 4 +
                      2ull * B_ * 32 * 16;            // ~28.3 MB

  if (ws_size >= NEED) {
    char* w = (char*)d_ws;
    unsigned short* Bp = (unsigned short*)w;
    float*  h0buf = (float*)(w + BP_BYTES);
    float*  h1buf = h0buf + (size_t)B_ * H_;
    float*  inp   = h1buf + (size_t)B_ * H_;
    float4* partA = (float4*)(inp + (size_t)B_ * EMB);
    float4* partB = partA + (size_t)B_ * 32;

    k_sos<<<dim3(B_ * EMB / 4 / 256), dim3(256), 0, stream>>>(sos, inp);
    k_prepack<<<dim3(2048), dim3(256), 0, stream>>>(W_out, Bp);
    k_gemm<<<dim3(1024), dim3(256), 0, stream>>>(
        h0buf, x, DIN, W_agent, nullptr, 0, nullptr, b_agent, nullptr, 0);

    for (int t = 0; t < TSTEPS; ++t) {
      float* hr = (t & 1) ? h1buf : h0buf;
      float* hw = (t & 1) ? h0buf : h1buf;
      k_gemm<<<dim3(1024), dim3(256), 0, stream>>>(
          hw, inp, EMB, W_ih, hr, H_, W_hh, b_ih, b_hh, 1);
      k_logits_mfma<<<dim3(1024), dim3(256), 0, stream>>>(
          hw, Bp, b_out, partA, partB);
      k_finalize2<<<dim3(256), dim3(256), 0, stream>>>(
          partA, partB, hw, W_out, b_out, emb, out, inp, t);
    }
  } else {
    float*  h0buf = (float*)d_ws;
    float*  h1buf = h0buf + (size_t)B_ * H_;
    float*  inp   = h1buf + (size_t)B_ * H_;
    float4* part  = (float4*)(inp + (size_t)B_ * EMB);

    k_sos<<<dim3(B_ * EMB / 4 / 256), dim3(256), 0, stream>>>(sos, inp);
    k_gemm<<<dim3(1024), dim3(256), 0, stream>>>(
        h0buf, x, DIN, W_agent, nullptr, 0, nullptr, b_agent, nullptr, 0);
    for (int t = 0; t < TSTEPS; ++t) {
      float* hr = (t & 1) ? h1buf : h0buf;
      float* hw = (t & 1) ? h0buf : h1buf;
      k_gemm<<<dim3(1024), dim3(256), 0, stream>>>(
          hw, inp, EMB, W_ih, hr, H_, W_hh, b_ih, b_hh, 1);
      k_logits_f32<<<dim3(B_ / BT, V_ / 512), dim3(256), 0, stream>>>(
          hw, W_out, b_out, part);
      k_finalize_f32<<<dim3(B_), dim3(128), 0, stream>>>(part, emb, out, inp, t);
    }
  }
  k_zero<<<dim3(12), dim3(256), 0, stream>>>(out);
}

// Round 5
// 2333.831 us; speedup vs baseline: 6.9796x; 2.2508x over previous
//
#include <hip/hip_runtime.h>
#include <math.h>

#define B_   1024
#define DIN  512
#define EMB  512
#define H_   1024
#define V_   4096
#define TSTEPS 32
#define LEN  33

typedef __attribute__((ext_vector_type(8))) short short8_t;
typedef __attribute__((ext_vector_type(4))) float f32x4;

// fragment-plane strides, in short8 (16B) units
#define AH_P  131072   // h A-frags: [p][rt64][ks32][lane64]
#define AI_P  65536    // inp A-frags: [p][rt64][ks16][lane64]
#define B3_P  196608   // W_ih|W_hh B-frags: [p][ks48][ntg64][lane64]
#define BPO_P 524288   // W_out B-frags: [p][ks32][ntg256][lane64]

__device__ inline unsigned short bf16_rne(float f) {
  unsigned u = __builtin_bit_cast(unsigned, f);
  u += 0x7FFFu + ((u >> 16) & 1u);
  return (unsigned short)(u >> 16);
}
__device__ inline float bf16_to_f(unsigned short h) {
  unsigned u = ((unsigned)h) << 16;
  return __builtin_bit_cast(float, u);
}
struct S3 { short a, b, c; };
__device__ inline S3 split3(float w) {
  unsigned short h0 = bf16_rne(w);  float r1 = w - bf16_to_f(h0);
  unsigned short h1 = bf16_rne(r1); float r2 = r1 - bf16_to_f(h1);
  S3 r; r.a = (short)h0; r.b = (short)h1; r.c = (short)bf16_rne(r2);
  return r;
}

#define T2MERGE(M1,I1,M2,I2, o1,oi1,o2,oi2)                              \
  if (o1 > M1 || (o1 == M1 && oi1 < I1)) {                               \
    float _n2; int _ni2;                                                 \
    if (M1 > o2 || (M1 == o2 && I1 < oi2)) { _n2 = M1; _ni2 = I1; }      \
    else { _n2 = o2; _ni2 = oi2; }                                       \
    M1 = o1; I1 = oi1; M2 = _n2; I2 = _ni2;                              \
  } else if (o1 > M2 || (o1 == M2 && oi1 < I2)) { M2 = o1; I2 = oi1; }

// ===========================================================================
// fp32 GEMM (agent h0 + fallback path): out = act(A1@W1 + A2@W2 + b1 + b2)
// ===========================================================================
#define GBT 4
#define GKC 256
__global__ __launch_bounds__(256) void k_gemm(
    float* __restrict__ out,
    const float* __restrict__ A1, int K1, const float* __restrict__ W1,
    const float* __restrict__ A2, int K2, const float* __restrict__ W2,
    const float* __restrict__ b1, const float* __restrict__ b2,
    int do_tanh)
{
  const int N = H_;
  __shared__ float sA[GBT][GKC];
  const int tid = threadIdx.x;
  const int bid = blockIdx.x;
  const int colb = (bid & 7) >> 1;
  const int rowb = ((bid >> 3) << 1) | (bid & 1);
  const int rb  = rowb * GBT;
  const int col = colb * 256 + tid;

  float acc[GBT];
  float bias = b1[col] + (b2 ? b2[col] : 0.0f);
#pragma unroll
  for (int r = 0; r < GBT; ++r) acc[r] = bias;

  const int nch = (K1 + K2) / GKC;
  for (int c = 0; c < nch; ++c) {
    const int kb = c * GKC;
    const float* A; const float* W; int k0, strideA;
    if (kb < K1) { A = A1; W = W1; k0 = kb;      strideA = K1; }
    else         { A = A2; W = W2; k0 = kb - K1; strideA = K2; }
    __syncthreads();
    {
      int r = tid >> 6, kk = (tid & 63) << 2;
      *(float4*)&sA[r][kk] = *(const float4*)(A + (size_t)(rb + r) * strideA + k0 + kk);
    }
    __syncthreads();
    const float* Wp = W + (size_t)k0 * N + col;
#pragma unroll 4
    for (int k = 0; k < GKC; k += 4) {
      float4 a0 = *(const float4*)&sA[0][k];
      float4 a1 = *(const float4*)&sA[1][k];
      float4 a2 = *(const float4*)&sA[2][k];
      float4 a3 = *(const float4*)&sA[3][k];
      float w0 = Wp[(size_t)k * N];
      float w1 = Wp[(size_t)(k + 1) * N];
      float w2 = Wp[(size_t)(k + 2) * N];
      float w3 = Wp[(size_t)(k + 3) * N];
      acc[0] = fmaf(a0.x, w0, acc[0]); acc[1] = fmaf(a1.x, w0, acc[1]);
      acc[2] = fmaf(a2.x, w0, acc[2]); acc[3] = fmaf(a3.x, w0, acc[3]);
      acc[0] = fmaf(a0.y, w1, acc[0]); acc[1] = fmaf(a1.y, w1, acc[1]);
      acc[2] = fmaf(a2.y, w1, acc[2]); acc[3] = fmaf(a3.y, w1, acc[3]);
      acc[0] = fmaf(a0.z, w2, acc[0]); acc[1] = fmaf(a1.z, w2, acc[1]);
      acc[2] = fmaf(a2.z, w2, acc[2]); acc[3] = fmaf(a3.z, w2, acc[3]);
      acc[0] = fmaf(a0.w, w3, acc[0]); acc[1] = fmaf(a1.w, w3, acc[1]);
      acc[2] = fmaf(a2.w, w3, acc[2]); acc[3] = fmaf(a3.w, w3, acc[3]);
    }
  }
#pragma unroll
  for (int r = 0; r < GBT; ++r) {
    float v = acc[r];
    if (do_tanh) v = tanhf(v);
    out[(size_t)(rb + r) * N + col] = v;
  }
}

// ===========================================================================
// One-time packs
// ===========================================================================
// W_out -> 2 bf16 planes, B-fragment order (hi/lo)
__global__ __launch_bounds__(256) void k_prepack(
    const float* __restrict__ W, unsigned short* __restrict__ Bp)
{
  int t = blockIdx.x * 256 + threadIdx.x;   // 524288 threads
  int lane = t & 63;
  int ntg  = (t >> 6) & 255;
  int ks   = t >> 14;
  int col  = ntg * 16 + (lane & 15);
  int krow = ks * 32 + ((lane >> 4) << 3);
  short8_t hv, lv;
#pragma unroll
  for (int j = 0; j < 8; ++j) {
    float w = W[(size_t)(krow + j) * V_ + col];
    unsigned short h = bf16_rne(w);
    hv[j] = (short)h;
    lv[j] = (short)bf16_rne(w - bf16_to_f(h));
  }
  size_t base = ((size_t)ks * 256 + ntg) * 64 + lane;
  short8_t* o = (short8_t*)Bp;
  o[base]         = hv;
  o[base + BPO_P] = lv;
}

// [W_ih ; W_hh] -> 3 bf16 planes, B-fragment order
__global__ __launch_bounds__(256) void k_packW3(
    const float* __restrict__ Wih, const float* __restrict__ Whh,
    unsigned short* __restrict__ BU)
{
  int t = blockIdx.x * 256 + threadIdx.x;   // 196608 threads
  int lane = t & 63;
  int ntg  = (t >> 6) & 63;
  int ks   = t >> 12;                        // 0..47
  int col  = ntg * 16 + (lane & 15);
  int krow = ks * 32 + ((lane >> 4) << 3);
  short8_t p0, p1, p2;
#pragma unroll
  for (int j = 0; j < 8; ++j) {
    int kr = krow + j;
    float w = (kr < DIN) ? Wih[(size_t)kr * H_ + col]
                         : Whh[(size_t)(kr - DIN) * H_ + col];
    S3 s = split3(w);
    p0[j] = s.a; p1[j] = s.b; p2[j] = s.c;
  }
  short8_t* o = (short8_t*)BU;
  size_t base = ((size_t)ks * 64 + ntg) * 64 + lane;
  o[base] = p0; o[base + B3_P] = p1; o[base + 2 * B3_P] = p2;
}

// W_out (1024x4096) -> transposed fp32 copy (4096x1024), 64x64 LDS tiles
__global__ __launch_bounds__(256) void k_wtrans(
    const float* __restrict__ W, float* __restrict__ WT)
{
  __shared__ float tile[64][65];
  int kb = (blockIdx.x & 15) * 64;
  int vb = (blockIdx.x >> 4) * 64;
  int t = threadIdx.x;
  {
    int vv = t & 63, k0 = (t >> 6) * 16;
    for (int j = 0; j < 16; ++j)
      tile[k0 + j][vv] = W[(size_t)(kb + k0 + j) * V_ + vb + vv];
  }
  __syncthreads();
  {
    int kk = t & 63, v0 = (t >> 6) * 16;
    for (int j = 0; j < 16; ++j)
      WT[(size_t)(vb + v0 + j) * H_ + kb + kk] = tile[kk][v0 + j];
  }
}

// h fp32 [B][H] -> 3-plane A-fragments (used once, for h0)
__global__ __launch_bounds__(256) void k_packh(
    const float* __restrict__ h, unsigned short* __restrict__ AU)
{
  int t = blockIdx.x * 256 + threadIdx.x;   // 131072 threads
  int r = t >> 7, q = t & 127;
  int ks = q >> 2, kg = q & 3;
  int lanep = (r & 15) + (kg << 4);
  int rt = r >> 4;
  const float* src = h + (size_t)r * H_ + q * 8;
  float4 f0 = *(const float4*)src;
  float4 f1 = *(const float4*)(src + 4);
  float f[8] = {f0.x, f0.y, f0.z, f0.w, f1.x, f1.y, f1.z, f1.w};
  short8_t p0, p1, p2;
#pragma unroll
  for (int j = 0; j < 8; ++j) {
    S3 s = split3(f[j]);
    p0[j] = s.a; p1[j] = s.b; p2[j] = s.c;
  }
  short8_t* o = (short8_t*)AU;
  size_t base = (size_t)rt * 2048 + (size_t)ks * 64 + lanep;
  o[base] = p0; o[base + AH_P] = p1; o[base + 2 * AH_P] = p2;
}

// sos -> inp A-fragments, all rows
__global__ __launch_bounds__(256) void k_sos3(
    const float* __restrict__ sos, unsigned short* __restrict__ AU)
{
  int wid = threadIdx.x >> 6, lane = threadIdx.x & 63;
  int row = blockIdx.x * 4 + wid;
  const float* src = sos + lane * 8;
  float4 f0 = *(const float4*)src;
  float4 f1 = *(const float4*)(src + 4);
  float f[8] = {f0.x, f0.y, f0.z, f0.w, f1.x, f1.y, f1.z, f1.w};
  short8_t p0, p1, p2;
#pragma unroll
  for (int j = 0; j < 8; ++j) {
    S3 s = split3(f[j]);
    p0[j] = s.a; p1[j] = s.b; p2[j] = s.c;
  }
  int ks = lane >> 2, kg = lane & 3;
  int lanep = (row & 15) + (kg << 4);
  int rt = row >> 4;
  short8_t* o = (short8_t*)AU;
  size_t base = (size_t)rt * 1024 + (size_t)ks * 64 + lanep;
  o[base] = p0; o[base + AI_P] = p1; o[base + 2 * AI_P] = p2;
}

// ===========================================================================
// RNN step GEMM: pre = inp@W_ih + h@W_hh + b_ih + b_hh (6-term split-bf16
// MFMA); h_new = tanh(pre). 256 blocks x 512 thr (8 waves: 2x2 tile waves
// x 2 K-halves). Block tile M=64 x N=64; wave tile 32x32. Epilogue packs
// h_new A-fragments for the next step (and logits).
// ===========================================================================
__global__ __launch_bounds__(512) void k_rnn(
    const unsigned short* __restrict__ AinpU, const unsigned short* __restrict__ AhU,
    const unsigned short* __restrict__ Bw3U,
    const float* __restrict__ b1, const float* __restrict__ b2,
    float* __restrict__ hout, unsigned short* __restrict__ AhOutU)
{
  __shared__ float sh[64][65];
  const short8_t* Ainp = (const short8_t*)AinpU;
  const short8_t* Ah   = (const short8_t*)AhU;
  const short8_t* Bw3  = (const short8_t*)Bw3U;

  const int bid  = blockIdx.x;
  const int colb = ((bid & 7) << 1) | ((bid >> 3) & 1);  // 0..15 (XCD-local)
  const int rowb = bid >> 4;                              // 0..15
  const int tid  = threadIdx.x, lane = tid & 63, wid = tid >> 6;
  const int wm = (wid >> 1) & 1, wn = wid & 1, kh = wid >> 2;
  const int l15 = lane & 15, lg = lane >> 4;

  f32x4 acc[2][2];
#pragma unroll
  for (int rt = 0; rt < 2; ++rt)
#pragma unroll
    for (int nt = 0; nt < 2; ++nt) {
      int col = colb * 64 + wn * 32 + nt * 16 + l15;
      float b = (kh == 0) ? (b1[col] + b2[col]) : 0.0f;
      acc[rt][nt] = (f32x4){b, b, b, b};
    }

  const int rt0 = rowb * 4 + wm * 2;
  const int ng0 = colb * 4 + wn * 2;
  const int ks0 = kh * 24;

#define RNN_LOAD(A_, B_, KS)                                                   \
  {                                                                            \
    int _ks = (KS);                                                            \
    if (_ks < 16) {                                                            \
      _Pragma("unroll") for (int rt = 0; rt < 2; ++rt)                         \
        _Pragma("unroll") for (int p = 0; p < 3; ++p)                          \
          A_[rt][p] = Ainp[(size_t)p * AI_P + (size_t)(rt0 + rt) * 1024 +      \
                           (size_t)_ks * 64 + lane];                           \
    } else {                                                                   \
      int _h = _ks - 16;                                                       \
      _Pragma("unroll") for (int rt = 0; rt < 2; ++rt)                         \
        _Pragma("unroll") for (int p = 0; p < 3; ++p)                          \
          A_[rt][p] = Ah[(size_t)p * AH_P + (size_t)(rt0 + rt) * 2048 +        \
                         (size_t)_h * 64 + lane];                              \
    }                                                                          \
    _Pragma("unroll") for (int nt = 0; nt < 2; ++nt)                           \
      _Pragma("unroll") for (int p = 0; p < 3; ++p)                            \
        B_[nt][p] = Bw3[(size_t)p * B3_P + (size_t)_ks * 4096 +                \
                        (size_t)(ng0 + nt) * 64 + lane];                       \
  }

  short8_t a[2][3], bb[2][3];
  RNN_LOAD(a, bb, ks0)
#pragma unroll
  for (int i = 0; i < 24; ++i) {
    short8_t an[2][3], bn[2][3];
    if (i < 23) RNN_LOAD(an, bn, ks0 + i + 1)
#pragma unroll
    for (int rt = 0; rt < 2; ++rt)
#pragma unroll
      for (int nt = 0; nt < 2; ++nt) {
        acc[rt][nt] = __builtin_amdgcn_mfma_f32_16x16x32_bf16(a[rt][0], bb[nt][0], acc[rt][nt], 0, 0, 0);
        acc[rt][nt] = __builtin_amdgcn_mfma_f32_16x16x32_bf16(a[rt][0], bb[nt][1], acc[rt][nt], 0, 0, 0);
        acc[rt][nt] = __builtin_amdgcn_mfma_f32_16x16x32_bf16(a[rt][1], bb[nt][0], acc[rt][nt], 0, 0, 0);
        acc[rt][nt] = __builtin_amdgcn_mfma_f32_16x16x32_bf16(a[rt][1], bb[nt][1], acc[rt][nt], 0, 0, 0);
        acc[rt][nt] = __builtin_amdgcn_mfma_f32_16x16x32_bf16(a[rt][0], bb[nt][2], acc[rt][nt], 0, 0, 0);
        acc[rt][nt] = __builtin_amdgcn_mfma_f32_16x16x32_bf16(a[rt][2], bb[nt][0], acc[rt][nt], 0, 0, 0);
      }
    if (i < 23) {
#pragma unroll
      for (int rt = 0; rt < 2; ++rt)
#pragma unroll
        for (int p = 0; p < 3; ++p) { a[rt][p] = an[rt][p]; bb[rt][p] = bn[rt][p]; }
    }
  }
#undef RNN_LOAD

  // K-half merge: kh=1 stores partials, kh=0 adds + tanh
  if (kh == 1) {
#pragma unroll
    for (int rt = 0; rt < 2; ++rt)
#pragma unroll
      for (int nt = 0; nt < 2; ++nt)
#pragma unroll
        for (int r = 0; r < 4; ++r)
          sh[wm * 32 + rt * 16 + lg * 4 + r][wn * 32 + nt * 16 + l15] = acc[rt][nt][r];
  }
  __syncthreads();
  if (kh == 0) {
#pragma unroll
    for (int rt = 0; rt < 2; ++rt)
#pragma unroll
      for (int nt = 0; nt < 2; ++nt)
#pragma unroll
        for (int r = 0; r < 4; ++r) {
          int lr = wm * 32 + rt * 16 + lg * 4 + r;
          int lc = wn * 32 + nt * 16 + l15;
          float v = tanhf(acc[rt][nt][r] + sh[lr][lc]);
          hout[(size_t)(rowb * 64 + lr) * H_ + colb * 64 + lc] = v;
          sh[lr][lc] = v;
        }
  }
  __syncthreads();
  // pack fragments: 64 rows x 8 octets = 512 tasks, 1 per thread
  {
    int lr = tid >> 3, q = tid & 7;
    int gk = colb * 64 + q * 8;
    int ks = gk >> 5, kg = (gk >> 3) & 3;
    int gr = rowb * 64 + lr;
    int lanep = (gr & 15) + (kg << 4);
    int rt = gr >> 4;
    short8_t p0, p1, p2;
#pragma unroll
    for (int j = 0; j < 8; ++j) {
      S3 s = split3(sh[lr][q * 8 + j]);
      p0[j] = s.a; p1[j] = s.b; p2[j] = s.c;
    }
    short8_t* o = (short8_t*)AhOutU;
    size_t base = (size_t)rt * 2048 + (size_t)ks * 64 + lanep;
    o[base] = p0; o[base + AH_P] = p1; o[base + 2 * AH_P] = p2;
  }
}

// ===========================================================================
// logits: h@W_out + b_out via 3-MFMA hi/lo split, from packed fragments.
// Grid 512 = rowb(16) x colb(32); block 4 waves (2x2); wave tile 32x64.
// Epilogue: per-row top-2 + exp-sum partials per 128-col block.
// ===========================================================================
__global__ __launch_bounds__(256) void k_logits3(
    const unsigned short* __restrict__ AhU, const unsigned short* __restrict__ BpU,
    const float* __restrict__ bout, float4* __restrict__ partA,
    float4* __restrict__ partB)
{
  __shared__ float sred[2][2][32][6];
  __shared__ float sbmax[64];
  const short8_t* Ah = (const short8_t*)AhU;
  const short8_t* Bp = (const short8_t*)BpU;

  const int bid  = blockIdx.x;
  const int colb = ((bid & 7) << 2) | ((bid >> 3) & 3);  // 0..31
  const int rowb = bid >> 5;                              // 0..15
  const int tid  = threadIdx.x, lane = tid & 63, wid = tid >> 6;
  const int wm = wid >> 1, wn = wid & 1;
  const int l15 = lane & 15, lg = lane >> 4;

  const int colbase = colb * 128 + wn * 64;
  f32x4 acc[2][4];
#pragma unroll
  for (int nt = 0; nt < 4; ++nt) {
    float b = bout[colbase + nt * 16 + l15];
    acc[0][nt] = (f32x4){b, b, b, b};
    acc[1][nt] = acc[0][nt];
  }
  const int rt0 = rowb * 4 + wm * 2;
  const int ng0 = colb * 8 + wn * 4;

#define LG_LOAD(A_, B_, KS)                                                    \
  {                                                                            \
    int _ks = (KS);                                                            \
    _Pragma("unroll") for (int rt = 0; rt < 2; ++rt)                           \
      _Pragma("unroll") for (int p = 0; p < 2; ++p)                            \
        A_[rt][p] = Ah[(size_t)p * AH_P + (size_t)(rt0 + rt) * 2048 +          \
                       (size_t)_ks * 64 + lane];                               \
    _Pragma("unroll") for (int nt = 0; nt < 4; ++nt)                           \
      _Pragma("unroll") for (int p = 0; p < 2; ++p)                            \
        B_[nt][p] = Bp[(size_t)p * BPO_P + ((size_t)_ks * 256 + ng0 + nt) * 64 \
                       + lane];                                                \
  }

  short8_t a[2][2], bb[4][2];
  LG_LOAD(a, bb, 0)
  for (int ks = 0; ks < 32; ++ks) {
    short8_t an[2][2], bn[4][2];
    if (ks < 31) LG_LOAD(an, bn, ks + 1)
#pragma unroll
    for (int rt = 0; rt < 2; ++rt)
#pragma unroll
      for (int nt = 0; nt < 4; ++nt) {
        acc[rt][nt] = __builtin_amdgcn_mfma_f32_16x16x32_bf16(a[rt][0], bb[nt][0], acc[rt][nt], 0, 0, 0);
        acc[rt][nt] = __builtin_amdgcn_mfma_f32_16x16x32_bf16(a[rt][0], bb[nt][1], acc[rt][nt], 0, 0, 0);
        acc[rt][nt] = __builtin_amdgcn_mfma_f32_16x16x32_bf16(a[rt][1], bb[nt][0], acc[rt][nt], 0, 0, 0);
      }
    if (ks < 31) {
#pragma unroll
      for (int rt = 0; rt < 2; ++rt)
#pragma unroll
        for (int p = 0; p < 2; ++p) a[rt][p] = an[rt][p];
#pragma unroll
      for (int nt = 0; nt < 4; ++nt)
#pragma unroll
        for (int p = 0; p < 2; ++p) bb[nt][p] = bn[nt][p];
    }
  }
#undef LG_LOAD

  // ---- epilogue: top-2 per row over this wave's 64 cols ----
#pragma unroll
  for (int rt = 0; rt < 2; ++rt)
#pragma unroll
    for (int r = 0; r < 4; ++r) {
      float M1 = -1e30f, M2 = -1e30f; int I1 = 0, I2 = 0;
#pragma unroll
      for (int nt = 0; nt < 4; ++nt) {
        float v = acc[rt][nt][r]; int c = colbase + nt * 16 + l15;
        if (v > M1) { M2 = M1; I2 = I1; M1 = v; I1 = c; }
        else if (v > M2) { M2 = v; I2 = c; }
      }
#pragma unroll
      for (int d = 1; d < 16; d <<= 1) {
        float o1 = __shfl_xor(M1, d); int oi1 = __shfl_xor(I1, d);
        float o2 = __shfl_xor(M2, d); int oi2 = __shfl_xor(I2, d);
        T2MERGE(M1, I1, M2, I2, o1, oi1, o2, oi2)
      }
      if (l15 == 0) {
        int rl = rt * 16 + lg * 4 + r;
        sred[wm][wn][rl][0] = M1; sred[wm][wn][rl][1] = (float)I1;
        sred[wm][wn][rl][2] = M2; sred[wm][wn][rl][3] = (float)I2;
      }
    }
  __syncthreads();
  if (tid < 64) {
    int wmm = tid >> 5, rl = tid & 31;
    float M1 = sred[wmm][0][rl][0]; int I1 = (int)sred[wmm][0][rl][1];
    float M2 = sred[wmm][0][rl][2]; int I2 = (int)sred[wmm][0][rl][3];
    float o1 = sred[wmm][1][rl][0]; int oi1 = (int)sred[wmm][1][rl][1];
    float o2 = sred[wmm][1][rl][2]; int oi2 = (int)sred[wmm][1][rl][3];
    T2MERGE(M1, I1, M2, I2, o1, oi1, o2, oi2)
    int row = rowb * 64 + wmm * 32 + rl;
    partA[(size_t)row * 32 + colb] = make_float4(M1, (float)I1, M2, (float)I2);
    sbmax[wmm * 32 + rl] = M1;
  }
  __syncthreads();
  // exp sums relative to block-col max
#pragma unroll
  for (int rt = 0; rt < 2; ++rt)
#pragma unroll
    for (int r = 0; r < 4; ++r) {
      float m = sbmax[wm * 32 + rt * 16 + lg * 4 + r];
      float s = 0.f, tsum = 0.f;
#pragma unroll
      for (int nt = 0; nt < 4; ++nt) {
        float d = acc[rt][nt][r] - m;
        float e = expf(d);
        s += e; tsum += d * e;
      }
#pragma unroll
      for (int d = 1; d < 16; d <<= 1) { s += __shfl_xor(s, d); tsum += __shfl_xor(tsum, d); }
      if (l15 == 0) {
        int rl = rt * 16 + lg * 4 + r;
        sred[wm][wn][rl][4] = s; sred[wm][wn][rl][5] = tsum;
      }
    }
  __syncthreads();
  if (tid < 64) {
    int wmm = tid >> 5, rl = tid & 31;
    float s = sred[wmm][0][rl][4] + sred[wmm][1][rl][4];
    float tsum = sred[wmm][0][rl][5] + sred[wmm][1][rl][5];
    int row = rowb * 64 + wmm * 32 + rl;
    partB[(size_t)row * 32 + colb] = make_float4(s, tsum, 0.f, 0.f);
  }
}

// ===========================================================================
// Finalize: merge 32 partials/row, fp32-exact top-2 recompute (argmax),
// outputs, next-step embedding fragments. One wave per row; grid 256.
// ===========================================================================
__global__ __launch_bounds__(256) void k_finalize3(
    const float4* __restrict__ partA, const float4* __restrict__ partB,
    const float* __restrict__ h, const float* __restrict__ Wout,
    const float* __restrict__ WoutT, const float* __restrict__ bout,
    const float* __restrict__ emb, float* __restrict__ out,
    unsigned short* __restrict__ AinpU, int tstep)
{
  const int lane = threadIdx.x & 63;
  const int wid  = threadIdx.x >> 6;
  const int row  = blockIdx.x * 4 + wid;

  float M1 = -1e30f, M2 = -1e30f; int I1 = 0, I2 = 0;
  float bm = -1e30f, s_l = 0.f, t_l = 0.f;
  if (lane < 32) {
    float4 pa = partA[(size_t)row * 32 + lane];
    float4 pb = partB[(size_t)row * 32 + lane];
    M1 = pa.x; I1 = (int)pa.y; M2 = pa.z; I2 = (int)pa.w;
    bm = pa.x; s_l = pb.x; t_l = pb.y;
  }
  for (int d = 1; d < 32; d <<= 1) {
    float o1 = __shfl_xor(M1, d); int oi1 = __shfl_xor(I1, d);
    float o2 = __shfl_xor(M2, d); int oi2 = __shfl_xor(I2, d);
    T2MERGE(M1, I1, M2, I2, o1, oi1, o2, oi2)
  }
  M1 = __shfl(M1, 0); I1 = __shfl(I1, 0);
  M2 = __shfl(M2, 0); I2 = __shfl(I2, 0);

  float e = (lane < 32) ? expf(bm - M1) : 0.f;
  float s = e * s_l;
  float tsum = e * (t_l + (bm - M1) * s_l);
  for (int d = 1; d < 64; d <<= 1) { s += __shfl_xor(s, d); tsum += __shfl_xor(tsum, d); }

  // exact fp32 dots for the two candidates
  const float* hrow = h + (size_t)row * H_;
  float d1 = 0.f, d2 = 0.f;
  if (WoutT) {
    const float* w1 = WoutT + (size_t)I1 * H_;
    const float* w2 = WoutT + (size_t)I2 * H_;
#pragma unroll 4
    for (int k = lane; k < H_; k += 64) {
      float hv = hrow[k];
      d1 = fmaf(hv, w1[k], d1);
      d2 = fmaf(hv, w2[k], d2);
    }
  } else {
    for (int k = lane; k < H_; k += 64) {
      float hv = hrow[k];
      d1 = fmaf(hv, Wout[(size_t)k * V_ + I1], d1);
      d2 = fmaf(hv, Wout[(size_t)k * V_ + I2], d2);
    }
  }
  for (int d = 1; d < 64; d <<= 1) { d1 += __shfl_xor(d1, d); d2 += __shfl_xor(d2, d); }
  d1 += bout[I1]; d2 += bout[I2];

  int tok; float ltok;
  if (d2 > d1 || (d2 == d1 && I2 < I1)) { tok = I2; ltok = d2; }
  else                                  { tok = I1; ltok = d1; }
  float lg_s = logf(s);
  if (lane == 0) {
    out[(size_t)row * LEN + tstep]                  = (float)tok;
    out[(size_t)(B_ * LEN) + row * LEN + tstep]     = ltok - M1 - lg_s;
    out[(size_t)(2 * B_ * LEN) + row * LEN + tstep] = lg_s - tsum / s;
  }
  // embedding -> inp fragments for next step
  const float* er = emb + (size_t)tok * EMB + lane * 8;
  float4 f0 = *(const float4*)er;
  float4 f1 = *(const float4*)(er + 4);
  float f[8] = {f0.x, f0.y, f0.z, f0.w, f1.x, f1.y, f1.z, f1.w};
  short8_t p0, p1, p2;
#pragma unroll
  for (int j = 0; j < 8; ++j) {
    S3 s3v = split3(f[j]);
    p0[j] = s3v.a; p1[j] = s3v.b; p2[j] = s3v.c;
  }
  int ks = lane >> 2, kg = lane & 3;
  int lanep = (row & 15) + (kg << 4);
  int rt = row >> 4;
  short8_t* o = (short8_t*)AinpU;
  size_t base = (size_t)rt * 1024 + (size_t)ks * 64 + lanep;
  o[base] = p0; o[base + AI_P] = p1; o[base + 2 * AI_P] = p2;
}

// ============================ fp32 fallback path ===========================
#define BT 16
#define KC 128
__global__ __launch_bounds__(256) void k_logits_f32(
    const float* __restrict__ h, const float* __restrict__ Wout,
    const float* __restrict__ bout, float4* __restrict__ part)
{
  __shared__ float sA[BT][KC];
  __shared__ float redf[4][BT];
  __shared__ float redf2[4][BT];
  __shared__ int   redi[4][BT];
  __shared__ float bm[BT];

  const int tid = threadIdx.x;
  const int rb  = blockIdx.x * BT;
  const int c0  = blockIdx.y * 512 + tid * 2;

  float acc[BT][2];
  float2 bj = *(const float2*)(bout + c0);
#pragma unroll
  for (int r = 0; r < BT; ++r) { acc[r][0] = bj.x; acc[r][1] = bj.y; }

  for (int kb = 0; kb < H_; kb += KC) {
    __syncthreads();
    {
      float4* s4 = (float4*)sA;
#pragma unroll
      for (int i = 0; i < 2; ++i) {
        int idx = tid + i * 256;
        int r = idx >> 5, kk = (idx & 31) << 2;
        s4[idx] = *(const float4*)(h + (size_t)(rb + r) * H_ + kb + kk);
      }
    }
    __syncthreads();
    const float* Wp = Wout + (size_t)kb * V_ + c0;
#pragma unroll 2
    for (int k = 0; k < KC; k += 4) {
      float4 a[BT];
#pragma unroll
      for (int r = 0; r < BT; ++r) a[r] = *((const float4*)sA[r] + (k >> 2));
      float2 w[4];
#pragma unroll
      for (int u = 0; u < 4; ++u) w[u] = *(const float2*)(Wp + (size_t)(k + u) * V_);
#pragma unroll
      for (int u = 0; u < 4; ++u)
#pragma unroll
        for (int r = 0; r < BT; ++r) {
          float av = ((const float*)&a[r])[u];
          acc[r][0] = fmaf(av, w[u].x, acc[r][0]);
          acc[r][1] = fmaf(av, w[u].y, acc[r][1]);
        }
    }
  }

  const int wid = tid >> 6, lane = tid & 63;
  float mx[BT]; int ix[BT];
#pragma unroll
  for (int r = 0; r < BT; ++r) {
    float m = acc[r][0]; int ii = c0;
    if (acc[r][1] > m) { m = acc[r][1]; ii = c0 + 1; }
    mx[r] = m; ix[r] = ii;
  }
#pragma unroll
  for (int r = 0; r < BT; ++r) {
    for (int d = 32; d; d >>= 1) {
      float ov = __shfl_xor(mx[r], d);
      int   oi = __shfl_xor(ix[r], d);
      if (ov > mx[r] || (ov == mx[r] && oi < ix[r])) { mx[r] = ov; ix[r] = oi; }
    }
  }
  if (lane == 0) {
#pragma unroll
    for (int r = 0; r < BT; ++r) { redf[wid][r] = mx[r]; redi[wid][r] = ix[r]; }
  }
  __syncthreads();
  if (tid < BT) {
    float m = redf[0][tid]; int ii = redi[0][tid];
    for (int w = 1; w < 4; ++w) {
      float ov = redf[w][tid]; int oi = redi[w][tid];
      if (ov > m || (ov == m && oi < ii)) { m = ov; ii = oi; }
    }
    bm[tid] = m; redi[0][tid] = ii;
  }
  __syncthreads();
  float ss[BT], tt[BT];
#pragma unroll
  for (int r = 0; r < BT; ++r) {
    float m = bm[r];
    float s = 0.f, t = 0.f;
#pragma unroll
    for (int j = 0; j < 2; ++j) {
      float d = acc[r][j] - m;
      float e2 = expf(d);
      s += e2; t += d * e2;
    }
    ss[r] = s; tt[r] = t;
  }
#pragma unroll
  for (int r = 0; r < BT; ++r) {
    for (int d = 32; d; d >>= 1) {
      ss[r] += __shfl_xor(ss[r], d);
      tt[r] += __shfl_xor(tt[r], d);
    }
  }
  if (lane == 0) {
#pragma unroll
    for (int r = 0; r < BT; ++r) { redf[wid][r] = ss[r]; redf2[wid][r] = tt[r]; }
  }
  __syncthreads();
  if (tid < BT) {
    float s = 0.f, t = 0.f;
    for (int w = 0; w < 4; ++w) { s += redf[w][tid]; t += redf2[w][tid]; }
    part[(size_t)(rb + tid) * 8 + blockIdx.y] =
        make_float4(bm[tid], s, t, (float)redi[0][tid]);
  }
}

__global__ __launch_bounds__(128) void k_finalize_f32(
    const float4* __restrict__ part, const float* __restrict__ emb,
    float* __restrict__ out, float* __restrict__ inp, int t)
{
  const int row = blockIdx.x;
  __shared__ int s_tok;
  if (threadIdx.x == 0) {
    float4 p[8];
#pragma unroll
    for (int i = 0; i < 8; ++i) p[i] = part[(size_t)row * 8 + i];
    float m = p[0].x; int tok = (int)p[0].w;
#pragma unroll
    for (int i = 1; i < 8; ++i)
      if (p[i].x > m) { m = p[i].x; tok = (int)p[i].w; }
    float S = 0.f, T = 0.f;
#pragma unroll
    for (int i = 0; i < 8; ++i) {
      float w = expf(p[i].x - m);
      S += w * p[i].y;
      T += w * (p[i].z + (p[i].x - m) * p[i].y);
    }
    float lp  = -logf(S);
    float ent = logf(S) - T / S;
    out[(size_t)row * LEN + t]                  = (float)tok;
    out[(size_t)(B_ * LEN) + row * LEN + t]     = lp;
    out[(size_t)(2 * B_ * LEN) + row * LEN + t] = ent;
    s_tok = tok;
  }
  __syncthreads();
  const float4* src = (const float4*)(emb + (size_t)s_tok * EMB);
  float4* dst = (float4*)(inp + (size_t)row * EMB);
  for (int i = threadIdx.x; i < EMB / 4; i += blockDim.x) dst[i] = src[i];
}

__global__ void k_sos(const float* __restrict__ sos, float* __restrict__ inp) {
  int i = blockIdx.x * blockDim.x + threadIdx.x;
  ((float4*)inp)[i] = ((const float4*)sos)[i & (EMB / 4 - 1)];
}
__global__ void k_zero(float* __restrict__ out) {
  int i = blockIdx.x * blockDim.x + threadIdx.x;
  if (i < 3 * B_) {
    int sec = i >> 10, row = i & (B_ - 1);
    out[(size_t)sec * (B_ * LEN) + (size_t)row * LEN + (LEN - 1)] = 0.f;
  }
}

extern "C" void kernel_launch(void* const* d_in, const int* in_sizes, int n_in,
                              void* d_out, int out_size, void* d_ws, size_t ws_size,
                              hipStream_t stream) {
  const float* x       = (const float*)d_in[0];
  const float* W_agent = (const float*)d_in[1];
  const float* b_agent = (const float*)d_in[2];
  const float* sos     = (const float*)d_in[3];
  const float* emb     = (const float*)d_in[4];
  const float* W_ih    = (const float*)d_in[5];
  const float* W_hh    = (const float*)d_in[6];
  const float* b_ih    = (const float*)d_in[7];
  const float* b_hh    = (const float*)d_in[8];
  const float* W_out   = (const float*)d_in[9];
  const float* b_out   = (const float*)d_in[10];
  float* out = (float*)d_out;

  const size_t SZ_BPOUT = 16777216;
  const size_t SZ_BW3   = 9437184;
  const size_t SZ_WT    = 16777216;
  const size_t SZ_AH    = 6291456;
  const size_t SZ_AINP  = 3145728;
  const size_t SZ_H     = 4194304;
  const size_t SZ_PART  = 524288;
  const size_t NEED_A = SZ_BPOUT + SZ_BW3 + SZ_WT + 2 * SZ_AH + SZ_AINP + SZ_H + 2 * SZ_PART;
  const size_t NEED_B = NEED_A - SZ_WT;

  if (ws_size >= NEED_B) {
    const bool useT = ws_size >= NEED_A;
    char* p = (char*)d_ws;
    unsigned short* BpOut = (unsigned short*)p; p += SZ_BPOUT;
    unsigned short* Bw3   = (unsigned short*)p; p += SZ_BW3;
    float* WoutT = nullptr;
    if (useT) { WoutT = (float*)p; p += SZ_WT; }
    unsigned short* Ah0  = (unsigned short*)p; p += SZ_AH;
    unsigned short* Ah1  = (unsigned short*)p; p += SZ_AH;
    unsigned short* Ainp = (unsigned short*)p; p += SZ_AINP;
    float*  hbuf  = (float*)p; p += SZ_H;
    float4* partA = (float4*)p; p += SZ_PART;
    float4* partB = (float4*)p;

    k_sos3<<<dim3(256), dim3(256), 0, stream>>>(sos, Ainp);
    k_prepack<<<dim3(2048), dim3(256), 0, stream>>>(W_out, BpOut);
    k_packW3<<<dim3(768), dim3(256), 0, stream>>>(W_ih, W_hh, Bw3);
    if (useT) k_wtrans<<<dim3(1024), dim3(256), 0, stream>>>(W_out, WoutT);
    k_gemm<<<dim3(1024), dim3(256), 0, stream>>>(
        hbuf, x, DIN, W_agent, nullptr, 0, nullptr, b_agent, nullptr, 0);
    k_packh<<<dim3(512), dim3(256), 0, stream>>>(hbuf, Ah0);

    for (int t = 0; t < TSTEPS; ++t) {
      unsigned short* AhIn  = (t & 1) ? Ah1 : Ah0;
      unsigned short* AhOut = (t & 1) ? Ah0 : Ah1;
      k_rnn<<<dim3(256), dim3(512), 0, stream>>>(
          Ainp, AhIn, Bw3, b_ih, b_hh, hbuf, AhOut);
      k_logits3<<<dim3(512), dim3(256), 0, stream>>>(
          AhOut, BpOut, b_out, partA, partB);
      k_finalize3<<<dim3(256), dim3(256), 0, stream>>>(
          partA, partB, hbuf, W_out, WoutT, b_out, emb, out, Ainp, t);
    }
  } else {
    float*  h0buf = (float*)d_ws;
    float*  h1buf = h0buf + (size_t)B_ * H_;
    float*  inp   = h1buf + (size_t)B_ * H_;
    float4* part  = (float4*)(inp + (size_t)B_ * EMB);

    k_sos<<<dim3(B_ * EMB / 4 / 256), dim3(256), 0, stream>>>(sos, inp);
    k_gemm<<<dim3(1024), dim3(256), 0, stream>>>(
        h0buf, x, DIN, W_agent, nullptr, 0, nullptr, b_agent, nullptr, 0);
    for (int t = 0; t < TSTEPS; ++t) {
      float* hr = (t & 1) ? h1buf : h0buf;
      float* hw = (t & 1) ? h0buf : h1buf;
      k_gemm<<<dim3(1024), dim3(256), 0, stream>>>(
          hw, inp, EMB, W_ih, hr, H_, W_hh, b_ih, b_hh, 1);
      k_logits_f32<<<dim3(B_ / BT, V_ / 512), dim3(256), 0, stream>>>(
          hw, W_out, b_out, part);
      k_finalize_f32<<<dim3(B_), dim3(128), 0, stream>>>(part, emb, out, inp, t);
    }
  }
  k_zero<<<dim3(12), dim3(256), 0, stream>>>(out);
}

// Round 6
// 1943.320 us; speedup vs baseline: 8.3821x; 1.2010x over previous
//
#include <hip/hip_runtime.h>
#include <math.h>

#define B_   1024
#define DIN  512
#define EMB  512
#define H_   1024
#define V_   4096
#define TSTEPS 32
#define LEN  33

typedef __attribute__((ext_vector_type(8))) short short8_t;
typedef __attribute__((ext_vector_type(4))) float f32x4;

// fragment-plane strides, in short8 (16B) units
#define AH_P  131072   // h A-frags: [p][rt64][ks32][lane64]
#define AI_P  65536    // inp A-frags: [p][rt64][ks16][lane64]
#define B3_P  196608   // W_ih|W_hh B-frags: [p][ks48][ntg64][lane64]
// W_out B-frags (single hi plane): [ks32][ntg256][lane64]

__device__ inline unsigned short bf16_rne(float f) {
  unsigned u = __builtin_bit_cast(unsigned, f);
  u += 0x7FFFu + ((u >> 16) & 1u);
  return (unsigned short)(u >> 16);
}
__device__ inline float bf16_to_f(unsigned short h) {
  unsigned u = ((unsigned)h) << 16;
  return __builtin_bit_cast(float, u);
}
struct S3 { short a, b, c; };
__device__ inline S3 split3(float w) {
  unsigned short h0 = bf16_rne(w);  float r1 = w - bf16_to_f(h0);
  unsigned short h1 = bf16_rne(r1); float r2 = r1 - bf16_to_f(h1);
  S3 r; r.a = (short)h0; r.b = (short)h1; r.c = (short)bf16_rne(r2);
  return r;
}

#define T2MERGE(M1,I1,M2,I2, o1,oi1,o2,oi2)                              \
  if (o1 > M1 || (o1 == M1 && oi1 < I1)) {                               \
    float _n2; int _ni2;                                                 \
    if (M1 > o2 || (M1 == o2 && I1 < oi2)) { _n2 = M1; _ni2 = I1; }      \
    else { _n2 = o2; _ni2 = oi2; }                                       \
    M1 = o1; I1 = oi1; M2 = _n2; I2 = _ni2;                              \
  } else if (o1 > M2 || (o1 == M2 && oi1 < I2)) { M2 = o1; I2 = oi1; }

// ===========================================================================
// fp32 GEMM (agent h0 + fallback path): out = act(A1@W1 + A2@W2 + b1 + b2)
// ===========================================================================
#define GBT 4
#define GKC 256
__global__ __launch_bounds__(256) void k_gemm(
    float* __restrict__ out,
    const float* __restrict__ A1, int K1, const float* __restrict__ W1,
    const float* __restrict__ A2, int K2, const float* __restrict__ W2,
    const float* __restrict__ b1, const float* __restrict__ b2,
    int do_tanh)
{
  const int N = H_;
  __shared__ float sA[GBT][GKC];
  const int tid = threadIdx.x;
  const int bid = blockIdx.x;
  const int colb = (bid & 7) >> 1;
  const int rowb = ((bid >> 3) << 1) | (bid & 1);
  const int rb  = rowb * GBT;
  const int col = colb * 256 + tid;

  float acc[GBT];
  float bias = b1[col] + (b2 ? b2[col] : 0.0f);
#pragma unroll
  for (int r = 0; r < GBT; ++r) acc[r] = bias;

  const int nch = (K1 + K2) / GKC;
  for (int c = 0; c < nch; ++c) {
    const int kb = c * GKC;
    const float* A; const float* W; int k0, strideA;
    if (kb < K1) { A = A1; W = W1; k0 = kb;      strideA = K1; }
    else         { A = A2; W = W2; k0 = kb - K1; strideA = K2; }
    __syncthreads();
    {
      int r = tid >> 6, kk = (tid & 63) << 2;
      *(float4*)&sA[r][kk] = *(const float4*)(A + (size_t)(rb + r) * strideA + k0 + kk);
    }
    __syncthreads();
    const float* Wp = W + (size_t)k0 * N + col;
#pragma unroll 4
    for (int k = 0; k < GKC; k += 4) {
      float4 a0 = *(const float4*)&sA[0][k];
      float4 a1 = *(const float4*)&sA[1][k];
      float4 a2 = *(const float4*)&sA[2][k];
      float4 a3 = *(const float4*)&sA[3][k];
      float w0 = Wp[(size_t)k * N];
      float w1 = Wp[(size_t)(k + 1) * N];
      float w2 = Wp[(size_t)(k + 2) * N];
      float w3 = Wp[(size_t)(k + 3) * N];
      acc[0] = fmaf(a0.x, w0, acc[0]); acc[1] = fmaf(a1.x, w0, acc[1]);
      acc[2] = fmaf(a2.x, w0, acc[2]); acc[3] = fmaf(a3.x, w0, acc[3]);
      acc[0] = fmaf(a0.y, w1, acc[0]); acc[1] = fmaf(a1.y, w1, acc[1]);
      acc[2] = fmaf(a2.y, w1, acc[2]); acc[3] = fmaf(a3.y, w1, acc[3]);
      acc[0] = fmaf(a0.z, w2, acc[0]); acc[1] = fmaf(a1.z, w2, acc[1]);
      acc[2] = fmaf(a2.z, w2, acc[2]); acc[3] = fmaf(a3.z, w2, acc[3]);
      acc[0] = fmaf(a0.w, w3, acc[0]); acc[1] = fmaf(a1.w, w3, acc[1]);
      acc[2] = fmaf(a2.w, w3, acc[2]); acc[3] = fmaf(a3.w, w3, acc[3]);
    }
  }
#pragma unroll
  for (int r = 0; r < GBT; ++r) {
    float v = acc[r];
    if (do_tanh) v = tanhf(v);
    out[(size_t)(rb + r) * N + col] = v;
  }
}

// ===========================================================================
// One-time packs
// ===========================================================================
// W_out -> single bf16 hi plane, B-fragment order
__global__ __launch_bounds__(256) void k_prepack(
    const float* __restrict__ W, unsigned short* __restrict__ Bp)
{
  int t = blockIdx.x * 256 + threadIdx.x;   // 524288 threads
  int lane = t & 63;
  int ntg  = (t >> 6) & 255;
  int ks   = t >> 14;
  int col  = ntg * 16 + (lane & 15);
  int krow = ks * 32 + ((lane >> 4) << 3);
  short8_t hv;
#pragma unroll
  for (int j = 0; j < 8; ++j) {
    float w = W[(size_t)(krow + j) * V_ + col];
    hv[j] = (short)bf16_rne(w);
  }
  size_t base = ((size_t)ks * 256 + ntg) * 64 + lane;
  ((short8_t*)Bp)[base] = hv;
}

// [W_ih ; W_hh] -> 3 bf16 planes, B-fragment order
__global__ __launch_bounds__(256) void k_packW3(
    const float* __restrict__ Wih, const float* __restrict__ Whh,
    unsigned short* __restrict__ BU)
{
  int t = blockIdx.x * 256 + threadIdx.x;   // 196608 threads
  int lane = t & 63;
  int ntg  = (t >> 6) & 63;
  int ks   = t >> 12;                        // 0..47
  int col  = ntg * 16 + (lane & 15);
  int krow = ks * 32 + ((lane >> 4) << 3);
  short8_t p0, p1, p2;
#pragma unroll
  for (int j = 0; j < 8; ++j) {
    int kr = krow + j;
    float w = (kr < DIN) ? Wih[(size_t)kr * H_ + col]
                         : Whh[(size_t)(kr - DIN) * H_ + col];
    S3 s = split3(w);
    p0[j] = s.a; p1[j] = s.b; p2[j] = s.c;
  }
  short8_t* o = (short8_t*)BU;
  size_t base = ((size_t)ks * 64 + ntg) * 64 + lane;
  o[base] = p0; o[base + B3_P] = p1; o[base + 2 * B3_P] = p2;
}

// W_out (1024x4096) -> transposed fp32 copy (4096x1024), 64x64 LDS tiles
__global__ __launch_bounds__(256) void k_wtrans(
    const float* __restrict__ W, float* __restrict__ WT)
{
  __shared__ float tile[64][65];
  int kb = (blockIdx.x & 15) * 64;
  int vb = (blockIdx.x >> 4) * 64;
  int t = threadIdx.x;
  {
    int vv = t & 63, k0 = (t >> 6) * 16;
    for (int j = 0; j < 16; ++j)
      tile[k0 + j][vv] = W[(size_t)(kb + k0 + j) * V_ + vb + vv];
  }
  __syncthreads();
  {
    int kk = t & 63, v0 = (t >> 6) * 16;
    for (int j = 0; j < 16; ++j)
      WT[(size_t)(vb + v0 + j) * H_ + kb + kk] = tile[kk][v0 + j];
  }
}

// h fp32 [B][H] -> 3-plane A-fragments (used once, for h0)
__global__ __launch_bounds__(256) void k_packh(
    const float* __restrict__ h, unsigned short* __restrict__ AU)
{
  int t = blockIdx.x * 256 + threadIdx.x;   // 131072 threads
  int r = t >> 7, q = t & 127;
  int ks = q >> 2, kg = q & 3;
  int lanep = (r & 15) + (kg << 4);
  int rt = r >> 4;
  const float* src = h + (size_t)r * H_ + q * 8;
  float4 f0 = *(const float4*)src;
  float4 f1 = *(const float4*)(src + 4);
  float f[8] = {f0.x, f0.y, f0.z, f0.w, f1.x, f1.y, f1.z, f1.w};
  short8_t p0, p1, p2;
#pragma unroll
  for (int j = 0; j < 8; ++j) {
    S3 s = split3(f[j]);
    p0[j] = s.a; p1[j] = s.b; p2[j] = s.c;
  }
  short8_t* o = (short8_t*)AU;
  size_t base = (size_t)rt * 2048 + (size_t)ks * 64 + lanep;
  o[base] = p0; o[base + AH_P] = p1; o[base + 2 * AH_P] = p2;
}

// sos -> inp A-fragments, all rows
__global__ __launch_bounds__(256) void k_sos3(
    const float* __restrict__ sos, unsigned short* __restrict__ AU)
{
  int wid = threadIdx.x >> 6, lane = threadIdx.x & 63;
  int row = blockIdx.x * 4 + wid;
  const float* src = sos + lane * 8;
  float4 f0 = *(const float4*)src;
  float4 f1 = *(const float4*)(src + 4);
  float f[8] = {f0.x, f0.y, f0.z, f0.w, f1.x, f1.y, f1.z, f1.w};
  short8_t p0, p1, p2;
#pragma unroll
  for (int j = 0; j < 8; ++j) {
    S3 s = split3(f[j]);
    p0[j] = s.a; p1[j] = s.b; p2[j] = s.c;
  }
  int ks = lane >> 2, kg = lane & 3;
  int lanep = (row & 15) + (kg << 4);
  int rt = row >> 4;
  short8_t* o = (short8_t*)AU;
  size_t base = (size_t)rt * 1024 + (size_t)ks * 64 + lanep;
  o[base] = p0; o[base + AI_P] = p1; o[base + 2 * AI_P] = p2;
}

// ===========================================================================
// RNN step GEMM: pre = inp@W_ih + h@W_hh + b_ih + b_hh (6-term split-bf16
// MFMA); h_new = tanh(pre). 256 blocks x 512 thr (8 waves: 2x2 tile waves
// x 2 K-halves). Block tile M=64 x N=64; wave tile 32x32. Epilogue packs
// h_new A-fragments for the next step (and logits).
// ===========================================================================
__global__ __launch_bounds__(512) void k_rnn(
    const unsigned short* __restrict__ AinpU, const unsigned short* __restrict__ AhU,
    const unsigned short* __restrict__ Bw3U,
    const float* __restrict__ b1, const float* __restrict__ b2,
    float* __restrict__ hout, unsigned short* __restrict__ AhOutU)
{
  __shared__ float sh[64][65];
  const short8_t* Ainp = (const short8_t*)AinpU;
  const short8_t* Ah   = (const short8_t*)AhU;
  const short8_t* Bw3  = (const short8_t*)Bw3U;

  const int bid  = blockIdx.x;
  const int colb = ((bid & 7) << 1) | ((bid >> 3) & 1);  // 0..15 (XCD-local)
  const int rowb = bid >> 4;                              // 0..15
  const int tid  = threadIdx.x, lane = tid & 63, wid = tid >> 6;
  const int wm = (wid >> 1) & 1, wn = wid & 1, kh = wid >> 2;
  const int l15 = lane & 15, lg = lane >> 4;

  f32x4 acc[2][2];
#pragma unroll
  for (int rt = 0; rt < 2; ++rt)
#pragma unroll
    for (int nt = 0; nt < 2; ++nt) {
      int col = colb * 64 + wn * 32 + nt * 16 + l15;
      float b = (kh == 0) ? (b1[col] + b2[col]) : 0.0f;
      acc[rt][nt] = (f32x4){b, b, b, b};
    }

  const int rt0 = rowb * 4 + wm * 2;
  const int ng0 = colb * 4 + wn * 2;
  const int ks0 = kh * 24;

#define RNN_LOAD(A_, B_, KS)                                                   \
  {                                                                            \
    int _ks = (KS);                                                            \
    if (_ks < 16) {                                                            \
      _Pragma("unroll") for (int rt = 0; rt < 2; ++rt)                         \
        _Pragma("unroll") for (int p = 0; p < 3; ++p)                          \
          A_[rt][p] = Ainp[(size_t)p * AI_P + (size_t)(rt0 + rt) * 1024 +      \
                           (size_t)_ks * 64 + lane];                           \
    } else {                                                                   \
      int _h = _ks - 16;                                                       \
      _Pragma("unroll") for (int rt = 0; rt < 2; ++rt)                         \
        _Pragma("unroll") for (int p = 0; p < 3; ++p)                          \
          A_[rt][p] = Ah[(size_t)p * AH_P + (size_t)(rt0 + rt) * 2048 +        \
                         (size_t)_h * 64 + lane];                              \
    }                                                                          \
    _Pragma("unroll") for (int nt = 0; nt < 2; ++nt)                           \
      _Pragma("unroll") for (int p = 0; p < 3; ++p)                            \
        B_[nt][p] = Bw3[(size_t)p * B3_P + (size_t)_ks * 4096 +                \
                        (size_t)(ng0 + nt) * 64 + lane];                       \
  }

  short8_t a[2][3], bb[2][3];
  RNN_LOAD(a, bb, ks0)
#pragma unroll
  for (int i = 0; i < 24; ++i) {
    short8_t an[2][3], bn[2][3];
    if (i < 23) RNN_LOAD(an, bn, ks0 + i + 1)
#pragma unroll
    for (int rt = 0; rt < 2; ++rt)
#pragma unroll
      for (int nt = 0; nt < 2; ++nt) {
        acc[rt][nt] = __builtin_amdgcn_mfma_f32_16x16x32_bf16(a[rt][0], bb[nt][0], acc[rt][nt], 0, 0, 0);
        acc[rt][nt] = __builtin_amdgcn_mfma_f32_16x16x32_bf16(a[rt][0], bb[nt][1], acc[rt][nt], 0, 0, 0);
        acc[rt][nt] = __builtin_amdgcn_mfma_f32_16x16x32_bf16(a[rt][1], bb[nt][0], acc[rt][nt], 0, 0, 0);
        acc[rt][nt] = __builtin_amdgcn_mfma_f32_16x16x32_bf16(a[rt][1], bb[nt][1], acc[rt][nt], 0, 0, 0);
        acc[rt][nt] = __builtin_amdgcn_mfma_f32_16x16x32_bf16(a[rt][0], bb[nt][2], acc[rt][nt], 0, 0, 0);
        acc[rt][nt] = __builtin_amdgcn_mfma_f32_16x16x32_bf16(a[rt][2], bb[nt][0], acc[rt][nt], 0, 0, 0);
      }
    if (i < 23) {
#pragma unroll
      for (int rt = 0; rt < 2; ++rt)
#pragma unroll
        for (int p = 0; p < 3; ++p) { a[rt][p] = an[rt][p]; bb[rt][p] = bn[rt][p]; }
    }
  }
#undef RNN_LOAD

  // K-half merge: kh=1 stores partials, kh=0 adds + tanh
  if (kh == 1) {
#pragma unroll
    for (int rt = 0; rt < 2; ++rt)
#pragma unroll
      for (int nt = 0; nt < 2; ++nt)
#pragma unroll
        for (int r = 0; r < 4; ++r)
          sh[wm * 32 + rt * 16 + lg * 4 + r][wn * 32 + nt * 16 + l15] = acc[rt][nt][r];
  }
  __syncthreads();
  if (kh == 0) {
#pragma unroll
    for (int rt = 0; rt < 2; ++rt)
#pragma unroll
      for (int nt = 0; nt < 2; ++nt)
#pragma unroll
        for (int r = 0; r < 4; ++r) {
          int lr = wm * 32 + rt * 16 + lg * 4 + r;
          int lc = wn * 32 + nt * 16 + l15;
          float v = tanhf(acc[rt][nt][r] + sh[lr][lc]);
          hout[(size_t)(rowb * 64 + lr) * H_ + colb * 64 + lc] = v;
          sh[lr][lc] = v;
        }
  }
  __syncthreads();
  // pack fragments: 64 rows x 8 octets = 512 tasks, 1 per thread
  {
    int lr = tid >> 3, q = tid & 7;
    int gk = colb * 64 + q * 8;
    int ks = gk >> 5, kg = (gk >> 3) & 3;
    int gr = rowb * 64 + lr;
    int lanep = (gr & 15) + (kg << 4);
    int rt = gr >> 4;
    short8_t p0, p1, p2;
#pragma unroll
    for (int j = 0; j < 8; ++j) {
      S3 s = split3(sh[lr][q * 8 + j]);
      p0[j] = s.a; p1[j] = s.b; p2[j] = s.c;
    }
    short8_t* o = (short8_t*)AhOutU;
    size_t base = (size_t)rt * 2048 + (size_t)ks * 64 + lanep;
    o[base] = p0; o[base + AH_P] = p1; o[base + 2 * AH_P] = p2;
  }
}

// ===========================================================================
// logits: h@W_out + b_out, SINGLE-plane bf16 MFMA (argmax exactness comes
// from finalize's fp32 top-2 recompute; lp/ent tolerate ~1e-3).
// Grid 512 = rowb(16) x colb(32); block 4 waves (2x2); wave tile 32x64.
// Fully-unrolled ks loop, 3-set rotating 2-deep prefetch.
// ===========================================================================
__global__ __launch_bounds__(256) void k_logits3(
    const unsigned short* __restrict__ AhU, const unsigned short* __restrict__ BpU,
    const float* __restrict__ bout, float4* __restrict__ partA,
    float4* __restrict__ partB)
{
  __shared__ float sred[2][2][32][6];
  __shared__ float sbmax[64];
  const short8_t* Ah = (const short8_t*)AhU;
  const short8_t* Bp = (const short8_t*)BpU;

  const int bid  = blockIdx.x;
  const int colb = ((bid & 7) << 2) | ((bid >> 3) & 3);  // 0..31
  const int rowb = bid >> 5;                              // 0..15
  const int tid  = threadIdx.x, lane = tid & 63, wid = tid >> 6;
  const int wm = wid >> 1, wn = wid & 1;
  const int l15 = lane & 15, lg = lane >> 4;

  const int colbase = colb * 128 + wn * 64;
  f32x4 acc[2][4];
#pragma unroll
  for (int nt = 0; nt < 4; ++nt) {
    float b = bout[colbase + nt * 16 + l15];
    acc[0][nt] = (f32x4){b, b, b, b};
    acc[1][nt] = acc[0][nt];
  }
  const int rt0 = rowb * 4 + wm * 2;
  const int ng0 = colb * 8 + wn * 4;

#define LG_LOAD(A_, B_, KS)                                                    \
  {                                                                            \
    int _ks = (KS);                                                            \
    _Pragma("unroll") for (int rt = 0; rt < 2; ++rt)                           \
      A_[rt] = Ah[(size_t)(rt0 + rt) * 2048 + (size_t)_ks * 64 + lane];        \
    _Pragma("unroll") for (int nt = 0; nt < 4; ++nt)                           \
      B_[nt] = Bp[((size_t)_ks * 256 + ng0 + nt) * 64 + lane];                 \
  }

  short8_t abuf[3][2], bbuf[3][4];
  LG_LOAD(abuf[0], bbuf[0], 0)
  LG_LOAD(abuf[1], bbuf[1], 1)
#pragma unroll
  for (int ks = 0; ks < 32; ++ks) {
    const int cur = ks % 3, nxt = (ks + 2) % 3;
    if (ks + 2 < 32) LG_LOAD(abuf[nxt], bbuf[nxt], ks + 2)
#pragma unroll
    for (int rt = 0; rt < 2; ++rt)
#pragma unroll
      for (int nt = 0; nt < 4; ++nt)
        acc[rt][nt] = __builtin_amdgcn_mfma_f32_16x16x32_bf16(
            abuf[cur][rt], bbuf[cur][nt], acc[rt][nt], 0, 0, 0);
  }
#undef LG_LOAD

  // ---- epilogue: top-2 per row over this wave's 64 cols ----
#pragma unroll
  for (int rt = 0; rt < 2; ++rt)
#pragma unroll
    for (int r = 0; r < 4; ++r) {
      float M1 = -1e30f, M2 = -1e30f; int I1 = 0, I2 = 0;
#pragma unroll
      for (int nt = 0; nt < 4; ++nt) {
        float v = acc[rt][nt][r]; int c = colbase + nt * 16 + l15;
        if (v > M1) { M2 = M1; I2 = I1; M1 = v; I1 = c; }
        else if (v > M2) { M2 = v; I2 = c; }
      }
#pragma unroll
      for (int d = 1; d < 16; d <<= 1) {
        float o1 = __shfl_xor(M1, d); int oi1 = __shfl_xor(I1, d);
        float o2 = __shfl_xor(M2, d); int oi2 = __shfl_xor(I2, d);
        T2MERGE(M1, I1, M2, I2, o1, oi1, o2, oi2)
      }
      if (l15 == 0) {
        int rl = rt * 16 + lg * 4 + r;
        sred[wm][wn][rl][0] = M1; sred[wm][wn][rl][1] = (float)I1;
        sred[wm][wn][rl][2] = M2; sred[wm][wn][rl][3] = (float)I2;
      }
    }
  __syncthreads();
  if (tid < 64) {
    int wmm = tid >> 5, rl = tid & 31;
    float M1 = sred[wmm][0][rl][0]; int I1 = (int)sred[wmm][0][rl][1];
    float M2 = sred[wmm][0][rl][2]; int I2 = (int)sred[wmm][0][rl][3];
    float o1 = sred[wmm][1][rl][0]; int oi1 = (int)sred[wmm][1][rl][1];
    float o2 = sred[wmm][1][rl][2]; int oi2 = (int)sred[wmm][1][rl][3];
    T2MERGE(M1, I1, M2, I2, o1, oi1, o2, oi2)
    int row = rowb * 64 + wmm * 32 + rl;
    partA[(size_t)row * 32 + colb] = make_float4(M1, (float)I1, M2, (float)I2);
    sbmax[wmm * 32 + rl] = M1;
  }
  __syncthreads();
  // exp sums relative to block-col max
#pragma unroll
  for (int rt = 0; rt < 2; ++rt)
#pragma unroll
    for (int r = 0; r < 4; ++r) {
      float m = sbmax[wm * 32 + rt * 16 + lg * 4 + r];
      float s = 0.f, tsum = 0.f;
#pragma unroll
      for (int nt = 0; nt < 4; ++nt) {
        float d = acc[rt][nt][r] - m;
        float e = expf(d);
        s += e; tsum += d * e;
      }
#pragma unroll
      for (int d = 1; d < 16; d <<= 1) { s += __shfl_xor(s, d); tsum += __shfl_xor(tsum, d); }
      if (l15 == 0) {
        int rl = rt * 16 + lg * 4 + r;
        sred[wm][wn][rl][4] = s; sred[wm][wn][rl][5] = tsum;
      }
    }
  __syncthreads();
  if (tid < 64) {
    int wmm = tid >> 5, rl = tid & 31;
    float s = sred[wmm][0][rl][4] + sred[wmm][1][rl][4];
    float tsum = sred[wmm][0][rl][5] + sred[wmm][1][rl][5];
    int row = rowb * 64 + wmm * 32 + rl;
    partB[(size_t)row * 32 + colb] = make_float4(s, tsum, 0.f, 0.f);
  }
}

// ===========================================================================
// Finalize: merge 32 partials/row, fp32-exact top-2 recompute (argmax),
// outputs, next-step embedding fragments. One wave per row; grid 256.
// ===========================================================================
__global__ __launch_bounds__(256) void k_finalize3(
    const float4* __restrict__ partA, const float4* __restrict__ partB,
    const float* __restrict__ h, const float* __restrict__ Wout,
    const float* __restrict__ WoutT, const float* __restrict__ bout,
    const float* __restrict__ emb, float* __restrict__ out,
    unsigned short* __restrict__ AinpU, int tstep)
{
  const int lane = threadIdx.x & 63;
  const int wid  = threadIdx.x >> 6;
  const int row  = blockIdx.x * 4 + wid;

  float M1 = -1e30f, M2 = -1e30f; int I1 = 0, I2 = 0;
  float bm = -1e30f, s_l = 0.f, t_l = 0.f;
  if (lane < 32) {
    float4 pa = partA[(size_t)row * 32 + lane];
    float4 pb = partB[(size_t)row * 32 + lane];
    M1 = pa.x; I1 = (int)pa.y; M2 = pa.z; I2 = (int)pa.w;
    bm = pa.x; s_l = pb.x; t_l = pb.y;
  }
  for (int d = 1; d < 32; d <<= 1) {
    float o1 = __shfl_xor(M1, d); int oi1 = __shfl_xor(I1, d);
    float o2 = __shfl_xor(M2, d); int oi2 = __shfl_xor(I2, d);
    T2MERGE(M1, I1, M2, I2, o1, oi1, o2, oi2)
  }
  M1 = __shfl(M1, 0); I1 = __shfl(I1, 0);
  M2 = __shfl(M2, 0); I2 = __shfl(I2, 0);

  float e = (lane < 32) ? expf(bm - M1) : 0.f;
  float s = e * s_l;
  float tsum = e * (t_l + (bm - M1) * s_l);
  for (int d = 1; d < 64; d <<= 1) { s += __shfl_xor(s, d); tsum += __shfl_xor(tsum, d); }

  // exact fp32 dots for the two candidates
  const float* hrow = h + (size_t)row * H_;
  float d1 = 0.f, d2 = 0.f;
  if (WoutT) {
    const float* w1 = WoutT + (size_t)I1 * H_;
    const float* w2 = WoutT + (size_t)I2 * H_;
#pragma unroll 4
    for (int k = lane; k < H_; k += 64) {
      float hv = hrow[k];
      d1 = fmaf(hv, w1[k], d1);
      d2 = fmaf(hv, w2[k], d2);
    }
  } else {
    for (int k = lane; k < H_; k += 64) {
      float hv = hrow[k];
      d1 = fmaf(hv, Wout[(size_t)k * V_ + I1], d1);
      d2 = fmaf(hv, Wout[(size_t)k * V_ + I2], d2);
    }
  }
  for (int d = 1; d < 64; d <<= 1) { d1 += __shfl_xor(d1, d); d2 += __shfl_xor(d2, d); }
  d1 += bout[I1]; d2 += bout[I2];

  int tok; float ltok;
  if (d2 > d1 || (d2 == d1 && I2 < I1)) { tok = I2; ltok = d2; }
  else                                  { tok = I1; ltok = d1; }
  float lg_s = logf(s);
  if (lane == 0) {
    out[(size_t)row * LEN + tstep]                  = (float)tok;
    out[(size_t)(B_ * LEN) + row * LEN + tstep]     = ltok - M1 - lg_s;
    out[(size_t)(2 * B_ * LEN) + row * LEN + tstep] = lg_s - tsum / s;
  }
  // embedding -> inp fragments for next step
  const float* er = emb + (size_t)tok * EMB + lane * 8;
  float4 f0 = *(const float4*)er;
  float4 f1 = *(const float4*)(er + 4);
  float f[8] = {f0.x, f0.y, f0.z, f0.w, f1.x, f1.y, f1.z, f1.w};
  short8_t p0, p1, p2;
#pragma unroll
  for (int j = 0; j < 8; ++j) {
    S3 s3v = split3(f[j]);
    p0[j] = s3v.a; p1[j] = s3v.b; p2[j] = s3v.c;
  }
  int ks = lane >> 2, kg = lane & 3;
  int lanep = (row & 15) + (kg << 4);
  int rt = row >> 4;
  short8_t* o = (short8_t*)AinpU;
  size_t base = (size_t)rt * 1024 + (size_t)ks * 64 + lanep;
  o[base] = p0; o[base + AI_P] = p1; o[base + 2 * AI_P] = p2;
}

// ============================ fp32 fallback path ===========================
#define BT 16
#define KC 128
__global__ __launch_bounds__(256) void k_logits_f32(
    const float* __restrict__ h, const float* __restrict__ Wout,
    const float* __restrict__ bout, float4* __restrict__ part)
{
  __shared__ float sA[BT][KC];
  __shared__ float redf[4][BT];
  __shared__ float redf2[4][BT];
  __shared__ int   redi[4][BT];
  __shared__ float bm[BT];

  const int tid = threadIdx.x;
  const int rb  = blockIdx.x * BT;
  const int c0  = blockIdx.y * 512 + tid * 2;

  float acc[BT][2];
  float2 bj = *(const float2*)(bout + c0);
#pragma unroll
  for (int r = 0; r < BT; ++r) { acc[r][0] = bj.x; acc[r][1] = bj.y; }

  for (int kb = 0; kb < H_; kb += KC) {
    __syncthreads();
    {
      float4* s4 = (float4*)sA;
#pragma unroll
      for (int i = 0; i < 2; ++i) {
        int idx = tid + i * 256;
        int r = idx >> 5, kk = (idx & 31) << 2;
        s4[idx] = *(const float4*)(h + (size_t)(rb + r) * H_ + kb + kk);
      }
    }
    __syncthreads();
    const float* Wp = Wout + (size_t)kb * V_ + c0;
#pragma unroll 2
    for (int k = 0; k < KC; k += 4) {
      float4 a[BT];
#pragma unroll
      for (int r = 0; r < BT; ++r) a[r] = *((const float4*)sA[r] + (k >> 2));
      float2 w[4];
#pragma unroll
      for (int u = 0; u < 4; ++u) w[u] = *(const float2*)(Wp + (size_t)(k + u) * V_);
#pragma unroll
      for (int u = 0; u < 4; ++u)
#pragma unroll
        for (int r = 0; r < BT; ++r) {
          float av = ((const float*)&a[r])[u];
          acc[r][0] = fmaf(av, w[u].x, acc[r][0]);
          acc[r][1] = fmaf(av, w[u].y, acc[r][1]);
        }
    }
  }

  const int wid = tid >> 6, lane = tid & 63;
  float mx[BT]; int ix[BT];
#pragma unroll
  for (int r = 0; r < BT; ++r) {
    float m = acc[r][0]; int ii = c0;
    if (acc[r][1] > m) { m = acc[r][1]; ii = c0 + 1; }
    mx[r] = m; ix[r] = ii;
  }
#pragma unroll
  for (int r = 0; r < BT; ++r) {
    for (int d = 32; d; d >>= 1) {
      float ov = __shfl_xor(mx[r], d);
      int   oi = __shfl_xor(ix[r], d);
      if (ov > mx[r] || (ov == mx[r] && oi < ix[r])) { mx[r] = ov; ix[r] = oi; }
    }
  }
  if (lane == 0) {
#pragma unroll
    for (int r = 0; r < BT; ++r) { redf[wid][r] = mx[r]; redi[wid][r] = ix[r]; }
  }
  __syncthreads();
  if (tid < BT) {
    float m = redf[0][tid]; int ii = redi[0][tid];
    for (int w = 1; w < 4; ++w) {
      float ov = redf[w][tid]; int oi = redi[w][tid];
      if (ov > m || (ov == m && oi < ii)) { m = ov; ii = oi; }
    }
    bm[tid] = m; redi[0][tid] = ii;
  }
  __syncthreads();
  float ss[BT], tt[BT];
#pragma unroll
  for (int r = 0; r < BT; ++r) {
    float m = bm[r];
    float s = 0.f, t = 0.f;
#pragma unroll
    for (int j = 0; j < 2; ++j) {
      float d = acc[r][j] - m;
      float e2 = expf(d);
      s += e2; t += d * e2;
    }
    ss[r] = s; tt[r] = t;
  }
#pragma unroll
  for (int r = 0; r < BT; ++r) {
    for (int d = 32; d; d >>= 1) {
      ss[r] += __shfl_xor(ss[r], d);
      tt[r] += __shfl_xor(tt[r], d);
    }
  }
  if (lane == 0) {
#pragma unroll
    for (int r = 0; r < BT; ++r) { redf[wid][r] = ss[r]; redf2[wid][r] = tt[r]; }
  }
  __syncthreads();
  if (tid < BT) {
    float s = 0.f, t = 0.f;
    for (int w = 0; w < 4; ++w) { s += redf[w][tid]; t += redf2[w][tid]; }
    part[(size_t)(rb + tid) * 8 + blockIdx.y] =
        make_float4(bm[tid], s, t, (float)redi[0][tid]);
  }
}

__global__ __launch_bounds__(128) void k_finalize_f32(
    const float4* __restrict__ part, const float* __restrict__ emb,
    float* __restrict__ out, float* __restrict__ inp, int t)
{
  const int row = blockIdx.x;
  __shared__ int s_tok;
  if (threadIdx.x == 0) {
    float4 p[8];
#pragma unroll
    for (int i = 0; i < 8; ++i) p[i] = part[(size_t)row * 8 + i];
    float m = p[0].x; int tok = (int)p[0].w;
#pragma unroll
    for (int i = 1; i < 8; ++i)
      if (p[i].x > m) { m = p[i].x; tok = (int)p[i].w; }
    float S = 0.f, T = 0.f;
#pragma unroll
    for (int i = 0; i < 8; ++i) {
      float w = expf(p[i].x - m);
      S += w * p[i].y;
      T += w * (p[i].z + (p[i].x - m) * p[i].y);
    }
    float lp  = -logf(S);
    float ent = logf(S) - T / S;
    out[(size_t)row * LEN + t]                  = (float)tok;
    out[(size_t)(B_ * LEN) + row * LEN + t]     = lp;
    out[(size_t)(2 * B_ * LEN) + row * LEN + t] = ent;
    s_tok = tok;
  }
  __syncthreads();
  const float4* src = (const float4*)(emb + (size_t)s_tok * EMB);
  float4* dst = (float4*)(inp + (size_t)row * EMB);
  for (int i = threadIdx.x; i < EMB / 4; i += blockDim.x) dst[i] = src[i];
}

__global__ void k_sos(const float* __restrict__ sos, float* __restrict__ inp) {
  int i = blockIdx.x * blockDim.x + threadIdx.x;
  ((float4*)inp)[i] = ((const float4*)sos)[i & (EMB / 4 - 1)];
}
__global__ void k_zero(float* __restrict__ out) {
  int i = blockIdx.x * blockDim.x + threadIdx.x;
  if (i < 3 * B_) {
    int sec = i >> 10, row = i & (B_ - 1);
    out[(size_t)sec * (B_ * LEN) + (size_t)row * LEN + (LEN - 1)] = 0.f;
  }
}

extern "C" void kernel_launch(void* const* d_in, const int* in_sizes, int n_in,
                              void* d_out, int out_size, void* d_ws, size_t ws_size,
                              hipStream_t stream) {
  const float* x       = (const float*)d_in[0];
  const float* W_agent = (const float*)d_in[1];
  const float* b_agent = (const float*)d_in[2];
  const float* sos     = (const float*)d_in[3];
  const float* emb     = (const float*)d_in[4];
  const float* W_ih    = (const float*)d_in[5];
  const float* W_hh    = (const float*)d_in[6];
  const float* b_ih    = (const float*)d_in[7];
  const float* b_hh    = (const float*)d_in[8];
  const float* W_out   = (const float*)d_in[9];
  const float* b_out   = (const float*)d_in[10];
  float* out = (float*)d_out;

  const size_t SZ_BPOUT = 8388608;   // single hi plane
  const size_t SZ_BW3   = 9437184;
  const size_t SZ_WT    = 16777216;
  const size_t SZ_AH    = 6291456;
  const size_t SZ_AINP  = 3145728;
  const size_t SZ_H     = 4194304;
  const size_t SZ_PART  = 524288;
  const size_t NEED_A = SZ_BPOUT + SZ_BW3 + SZ_WT + 2 * SZ_AH + SZ_AINP + SZ_H + 2 * SZ_PART;
  const size_t NEED_B = NEED_A - SZ_WT;

  if (ws_size >= NEED_B) {
    const bool useT = ws_size >= NEED_A;
    char* p = (char*)d_ws;
    unsigned short* BpOut = (unsigned short*)p; p += SZ_BPOUT;
    unsigned short* Bw3   = (unsigned short*)p; p += SZ_BW3;
    float* WoutT = nullptr;
    if (useT) { WoutT = (float*)p; p += SZ_WT; }
    unsigned short* Ah0  = (unsigned short*)p; p += SZ_AH;
    unsigned short* Ah1  = (unsigned short*)p; p += SZ_AH;
    unsigned short* Ainp = (unsigned short*)p; p += SZ_AINP;
    float*  hbuf  = (float*)p; p += SZ_H;
    float4* partA = (float4*)p; p += SZ_PART;
    float4* partB = (float4*)p;

    k_sos3<<<dim3(256), dim3(256), 0, stream>>>(sos, Ainp);
    k_prepack<<<dim3(2048), dim3(256), 0, stream>>>(W_out, BpOut);
    k_packW3<<<dim3(768), dim3(256), 0, stream>>>(W_ih, W_hh, Bw3);
    if (useT) k_wtrans<<<dim3(1024), dim3(256), 0, stream>>>(W_out, WoutT);
    k_gemm<<<dim3(1024), dim3(256), 0, stream>>>(
        hbuf, x, DIN, W_agent, nullptr, 0, nullptr, b_agent, nullptr, 0);
    k_packh<<<dim3(512), dim3(256), 0, stream>>>(hbuf, Ah0);

    for (int t = 0; t < TSTEPS; ++t) {
      unsigned short* AhIn  = (t & 1) ? Ah1 : Ah0;
      unsigned short* AhOut = (t & 1) ? Ah0 : Ah1;
      k_rnn<<<dim3(256), dim3(512), 0, stream>>>(
          Ainp, AhIn, Bw3, b_ih, b_hh, hbuf, AhOut);
      k_logits3<<<dim3(512), dim3(256), 0, stream>>>(
          AhOut, BpOut, b_out, partA, partB);
      k_finalize3<<<dim3(256), dim3(256), 0, stream>>>(
          partA, partB, hbuf, W_out, WoutT, b_out, emb, out, Ainp, t);
    }
  } else {
    float*  h0buf = (float*)d_ws;
    float*  h1buf = h0buf + (size_t)B_ * H_;
    float*  inp   = h1buf + (size_t)B_ * H_;
    float4* part  = (float4*)(inp + (size_t)B_ * EMB);

    k_sos<<<dim3(B_ * EMB / 4 / 256), dim3(256), 0, stream>>>(sos, inp);
    k_gemm<<<dim3(1024), dim3(256), 0, stream>>>(
        h0buf, x, DIN, W_agent, nullptr, 0, nullptr, b_agent, nullptr, 0);
    for (int t = 0; t < TSTEPS; ++t) {
      float* hr = (t & 1) ? h1buf : h0buf;
      float* hw = (t & 1) ? h0buf : h1buf;
      k_gemm<<<dim3(1024), dim3(256), 0, stream>>>(
          hw, inp, EMB, W_ih, hr, H_, W_hh, b_ih, b_hh, 1);
      k_logits_f32<<<dim3(B_ / BT, V_ / 512), dim3(256), 0, stream>>>(
          hw, W_out, b_out, part);
      k_finalize_f32<<<dim3(B_), dim3(128), 0, stream>>>(part, emb, out, inp, t);
    }
  }
  k_zero<<<dim3(12), dim3(256), 0, stream>>>(out);
}